// Round 3
// 1107.833 us; speedup vs baseline: 1.0247x; 1.0247x over previous
//
#include <hip/hip_runtime.h>
#include <math.h>

typedef unsigned short ushort_t;                       // bf16 bit storage
typedef __bf16 bf16x8 __attribute__((ext_vector_type(8)));
typedef float  f32x4  __attribute__((ext_vector_type(4)));

constexpr int NN = 20000;   // nodes
constexpr int EE = 320000;  // edges
constexpr int NC = 2304;    // 9*256 projection width (8 rels + self-loop)
constexpr int TD = 2880;    // time dim

__device__ __forceinline__ float b2f(ushort_t u) {
    return __uint_as_float(((unsigned int)u) << 16);
}
__device__ __forceinline__ ushort_t f2b(float f) {
    unsigned int u = __float_as_uint(f);
    u += 0x7fffu + ((u >> 16) & 1u);                   // round-to-nearest-even
    return (ushort_t)(u >> 16);
}
// dual-dtype load: raw inputs may be f32 or bf16 (runtime-detected flag)
__device__ __forceinline__ float ldf(const void* p, size_t i, int f32m) {
    return f32m ? ((const float*)p)[i] : b2f(((const ushort_t*)p)[i]);
}
// async global->LDS, 16B per lane; LDS dest = wave-uniform base + lane*16
__device__ __forceinline__ void gl2lds16(const ushort_t* g, ushort_t* l) {
    __builtin_amdgcn_global_load_lds(
        (const __attribute__((address_space(1))) void*)g,
        (__attribute__((address_space(3))) void*)l, 16, 0, 0);
}

// shared MFMA inner step: LDS tiles [128 rows x 32 k] -> 4x4 acc of 16x16x32
__device__ __forceinline__ void mfma_step(const ushort_t* As, const ushort_t* Bs,
                                          f32x4 (&acc)[4][4],
                                          int wm, int wn, int quad, int l16)
{
    bf16x8 afr[4], bfr[4];
#pragma unroll
    for (int mi = 0; mi < 4; mi++)
        afr[mi] = *(const bf16x8*)(As + (wm * 64 + mi * 16 + l16) * 32 + quad * 8);
#pragma unroll
    for (int ni = 0; ni < 4; ni++)
        bfr[ni] = *(const bf16x8*)(Bs + (wn * 64 + ni * 16 + l16) * 32 + quad * 8);
#pragma unroll
    for (int mi = 0; mi < 4; mi++)
#pragma unroll
        for (int ni = 0; ni < 4; ni++)
            acc[mi][ni] = __builtin_amdgcn_mfma_f32_16x16x32_bf16(
                afr[mi], bfr[ni], acc[mi][ni], 0, 0, 0);
}

// ---------------------------------------------------------------------------
// Detect input dtype (bf16-stored vs f32-stored). flags[0]=f32mode, flags[1]=0.
// ---------------------------------------------------------------------------
__global__ void k_detect(const void* timeD, int* flags)
{
    __shared__ float mx[256];
    int t = threadIdx.x;
    float m = 0.f;
    for (int i = t; i < 1024; i += 256) {
        float v = fabsf(b2f(((const ushort_t*)timeD)[i]));
        if (!(v < 1e30f)) v = 1e30f;   // NaN/Inf -> huge
        m = fmaxf(m, v);
    }
    mx[t] = m;
    __syncthreads();
    if (t == 0) {
        float mm = 0.f;
        for (int i = 0; i < 256; i++) mm = fmaxf(mm, mx[i]);
        flags[0] = (mm > 1e4f) ? 1 : 0;
        flags[1] = 0;
    }
}

// small dtype-normalizing copy: out (bf16) <- in (f32 or bf16)
__global__ void k_cvt16(const void* __restrict__ in, ushort_t* __restrict__ out,
                        int n, const int* __restrict__ mf)
{
    int f32m = mf[0];
    int i = blockIdx.x * 256 + threadIdx.x;
    if (i < n) out[i] = f32m ? f2b(((const float*)in)[i]) : ((const ushort_t*)in)[i];
}

// ---------------------------------------------------------------------------
// Main bf16 MFMA GEMM (A is a ws bf16 buffer): C = act(A * Bt^T + bias).
// global_load_lds width-16 staging; LDS row stride 32 shorts (64B) so the
// lane->LDS map is linear (wave-uniform base + lane*16). 2-way bank alias on
// ds_read_b128 is free (m136). Tile 128x128, BK=32, 4 waves (2x2).
// A rows may over-read past M (stays inside d_ws; epilogue masks stores).
// Ncols must be a multiple of 128 (true for 2304/256).
// ---------------------------------------------------------------------------
__global__ __launch_bounds__(256) void gemm_bt(
    const ushort_t* __restrict__ A, int lda,
    const ushort_t* __restrict__ Bt, int ldb,
    void* __restrict__ C, int ldc, int col0, const int* __restrict__ of,
    const ushort_t* __restrict__ bias,
    int M, int Ncols, int K, int act)
{
    __shared__ ushort_t As[128 * 32];
    __shared__ ushort_t Bs[128 * 32];

    const int f32o = of[0];
    const int t    = threadIdx.x;
    const int wave = t >> 6, lane = t & 63;
    const int wm   = wave >> 1, wn = wave & 1;
    const int quad = lane >> 4, l16 = lane & 15;
    const int m0   = blockIdx.x * 128, n0 = blockIdx.y * 128;

    f32x4 acc[4][4];
#pragma unroll
    for (int i = 0; i < 4; i++)
#pragma unroll
        for (int j = 0; j < 4; j++) acc[i][j] = (f32x4){0.f, 0.f, 0.f, 0.f};

    for (int k0 = 0; k0 < K; k0 += 32) {
#pragma unroll
        for (int j = 0; j < 2; j++) {
            int c   = (wave * 2 + j) * 64 + lane;     // 16B chunk id, 512 total
            int row = c >> 2, kc = c & 3;
            ushort_t* ldsbase_a = As + (wave * 2 + j) * 512;  // wave-uniform
            ushort_t* ldsbase_b = Bs + (wave * 2 + j) * 512;
            gl2lds16(A  + (size_t)(m0 + row) * lda + k0 + kc * 8, ldsbase_a);
            gl2lds16(Bt + (size_t)(n0 + row) * ldb + k0 + kc * 8, ldsbase_b);
        }
        __syncthreads();
        mfma_step(As, Bs, acc, wm, wn, quad, l16);
        __syncthreads();
    }

#pragma unroll
    for (int mi = 0; mi < 4; mi++) {
#pragma unroll
        for (int r = 0; r < 4; r++) {
            int row = m0 + wm * 64 + mi * 16 + quad * 4 + r;
            if (row >= M) continue;
#pragma unroll
            for (int ni = 0; ni < 4; ni++) {
                int col = n0 + wn * 64 + ni * 16 + l16;
                float v = acc[mi][ni][r];
                if (bias) v += b2f(bias[col]);
                if (act == 1) v = fmaxf(v, 0.f);
                else if (act == 2) v = 0.5f * v * (1.f + erff(v * 0.70710678118654752f));
                size_t idx = (size_t)row * ldc + col0 + col;
                if (f32o) ((float*)C)[idx] = v;
                else      ((ushort_t*)C)[idx] = f2b(v);
            }
        }
    }
}

// ---------------------------------------------------------------------------
// Split-K GEMM for the time projection (A raw f32 or bf16, N=128 fixed).
// grid (m_tiles, ksplit); partial tiles atomicAdd into out128[M,128] f32.
// bf16 + full m-tile: async global_load_lds staging (proven gemm_bt pattern,
// no clamping, all rows in-bounds). Otherwise (f32 input, or the single
// partial last tile): dual-dtype VGPR staging with guarded rows, zero-fill.
// ---------------------------------------------------------------------------
__global__ __launch_bounds__(256) void gemm_splitk(
    const void* __restrict__ A, int lda, const int* __restrict__ af,
    const ushort_t* __restrict__ Bt, int ldb,
    float* __restrict__ out128, int M, int K, int KC)
{
    __shared__ ushort_t As[128 * 32];
    __shared__ ushort_t Bs[128 * 32];

    const int f32a = af[0];
    const int t    = threadIdx.x;
    const int wave = t >> 6, lane = t & 63;
    const int wm   = wave >> 1, wn = wave & 1;
    const int quad = lane >> 4, l16 = lane & 15;
    const int m0   = blockIdx.x * 128;
    const int kbeg = blockIdx.y * KC;
    const int kend = (kbeg + KC < K) ? kbeg + KC : K;

    f32x4 acc[4][4];
#pragma unroll
    for (int i = 0; i < 4; i++)
#pragma unroll
        for (int j = 0; j < 4; j++) acc[i][j] = (f32x4){0.f, 0.f, 0.f, 0.f};

    if (!f32a && (m0 + 128 <= M)) {
        // ---- bf16 full-tile fast path: async DMA staging (no guards) ----
        const ushort_t* Ab = (const ushort_t*)A;
        for (int k0 = kbeg; k0 < kend; k0 += 32) {
#pragma unroll
            for (int j = 0; j < 2; j++) {
                int c   = (wave * 2 + j) * 64 + lane;
                int row = c >> 2, kc = c & 3;
                gl2lds16(Ab + (size_t)(m0 + row) * lda + k0 + kc * 8,
                         As + (wave * 2 + j) * 512);
                gl2lds16(Bt + (size_t)row * ldb + k0 + kc * 8,
                         Bs + (wave * 2 + j) * 512);
            }
            __syncthreads();
            mfma_step(As, Bs, acc, wm, wn, quad, l16);
            __syncthreads();
        }
    } else {
        // ---- dual-dtype VGPR staging (guarded rows, zero-fill) ----
        for (int k0 = kbeg; k0 < kend; k0 += 32) {
#pragma unroll
            for (int i = 0; i < 2; i++) {
                int c = t + i * 256;              // 512 chunks of 8 elements
                int row = c >> 2, kc = c & 3;
                uint4 av = make_uint4(0, 0, 0, 0);
                int gr = m0 + row;
                if (gr < M) {
                    size_t base = (size_t)gr * lda + k0 + kc * 8;
                    if (f32a) {
                        const float* Af = (const float*)A + base;
                        float4 lo = *(const float4*)Af;
                        float4 hi = *(const float4*)(Af + 4);
                        av.x = (unsigned)f2b(lo.x) | ((unsigned)f2b(lo.y) << 16);
                        av.y = (unsigned)f2b(lo.z) | ((unsigned)f2b(lo.w) << 16);
                        av.z = (unsigned)f2b(hi.x) | ((unsigned)f2b(hi.y) << 16);
                        av.w = (unsigned)f2b(hi.z) | ((unsigned)f2b(hi.w) << 16);
                    } else {
                        av = *(const uint4*)((const ushort_t*)A + base);
                    }
                }
                *(uint4*)(As + row * 32 + kc * 8) = av;
                uint4 bv = *(const uint4*)(Bt + (size_t)row * ldb + k0 + kc * 8);
                *(uint4*)(Bs + row * 32 + kc * 8) = bv;
            }
            __syncthreads();
            mfma_step(As, Bs, acc, wm, wn, quad, l16);
            __syncthreads();
        }
    }

#pragma unroll
    for (int mi = 0; mi < 4; mi++) {
#pragma unroll
        for (int r = 0; r < 4; r++) {
            int row = m0 + wm * 64 + mi * 16 + quad * 4 + r;
            if (row >= M) continue;
#pragma unroll
            for (int ni = 0; ni < 4; ni++) {
                int col = wn * 64 + ni * 16 + l16;
                atomicAdd(out128 + (size_t)row * 128 + col, acc[mi][ni][r]);
            }
        }
    }
}

// feat cols 64..191 <- accf + b_time; grid NN, 128 threads
__global__ void k_bias_time(const float* __restrict__ accf,
                            const ushort_t* __restrict__ bt,
                            ushort_t* __restrict__ feat)
{
    int n = blockIdx.x, o = threadIdx.x;
    feat[(size_t)n * 256 + 64 + o] = f2b(accf[(size_t)n * 128 + o] + b2f(bt[o]));
}

// ---------------------------------------------------------------------------
// Build Wcat_t [2304(=9*256), 256]: row r*256+o holds column o of W_r over k.
// r<8: W_r = sum_b coeff[r,b]*bases[b];  r==8: self-loop weight.
// ---------------------------------------------------------------------------
__global__ void k_build_wcat(const void* __restrict__ coeff,
                             const void* __restrict__ bases,
                             const void* __restrict__ loopw,
                             ushort_t* __restrict__ Wt, const int* __restrict__ mf)
{
    int f32m = mf[0];
    int r = blockIdx.x >> 8, k = blockIdx.x & 255, o = threadIdx.x;
    float acc;
    if (r == 8) {
        acc = ldf(loopw, k * 256 + o, f32m);
    } else {
        acc = 0.f;
#pragma unroll
        for (int b = 0; b < 8; b++)
            acc += ldf(coeff, r * 8 + b, f32m) * ldf(bases, ((size_t)b * 256 + k) * 256 + o, f32m);
    }
    Wt[((size_t)(r * 256 + o)) * 256 + k] = f2b(acc);
}

// transpose raw [rows,cols] -> ws bf16 [cols,rows]
__global__ void k_transpose(const void* __restrict__ in, ushort_t* __restrict__ out,
                            int rows, int cols, const int* __restrict__ mf)
{
    int f32m = mf[0];
    int k = blockIdx.x, o = threadIdx.x;
    out[(size_t)o * rows + k] = f2b(ldf(in, (size_t)k * cols + o, f32m));
}

// Wfuse_t [256, 512] + bias_cat[o] = b_fuse[o] + b_fuse_kg[o]
__global__ void k_build_wfuse(const void* __restrict__ Wf, const void* __restrict__ Wfk,
                              const void* __restrict__ bf, const void* __restrict__ bfk,
                              ushort_t* __restrict__ Wt, ushort_t* __restrict__ bias_cat,
                              const int* __restrict__ mf)
{
    int f32m = mf[0];
    int k = blockIdx.x, o = threadIdx.x;
    float v = (k < 256) ? ldf(Wf, k * 256 + o, f32m) : ldf(Wfk, (k - 256) * 256 + o, f32m);
    Wt[(size_t)o * 512 + k] = f2b(v);
    if (k == 0) bias_cat[o] = f2b(ldf(bf, o, f32m) + ldf(bfk, o, f32m));
}

// poi (64 cols @0) + road (64 cols @192) projections; grid NN, 128 threads
__global__ void k_inproj(const void* __restrict__ poi, const void* __restrict__ Wp,
                         const void* __restrict__ bp,
                         const void* __restrict__ road, const void* __restrict__ Wr,
                         const void* __restrict__ br,
                         ushort_t* __restrict__ feat, const int* __restrict__ mf)
{
    int f32m = mf[0];
    int n = blockIdx.x, t = threadIdx.x;
    if (t < 64) {
        float a = ldf(bp, t, f32m);
#pragma unroll
        for (int k = 0; k < 12; k++)
            a += ldf(poi, (size_t)n * 12 + k, f32m) * ldf(Wp, k * 64 + t, f32m);
        feat[(size_t)n * 256 + t] = f2b(a);
    } else {
        int o = t - 64;
        float a = ldf(br, o, f32m);
#pragma unroll
        for (int k = 0; k < 32; k++)
            a += ldf(road, (size_t)n * 32 + k, f32m) * ldf(Wr, k * 64 + o, f32m);
        feat[(size_t)n * 256 + 192 + o] = f2b(a);
    }
}

// ------------------------- CSR build (per graph) ---------------------------
__global__ void k_zero(int* __restrict__ p, int n)
{
    int i = blockIdx.x * 256 + threadIdx.x;
    if (i < n) p[i] = 0;
}
__global__ void k_count(const int* __restrict__ dst, int* __restrict__ deg, int e)
{
    int i = blockIdx.x * 256 + threadIdx.x;
    if (i < e) atomicAdd(&deg[dst[i]], 1);
}
__global__ void k_scan1(const int* __restrict__ deg, int* __restrict__ partial,
                        int* __restrict__ bsum, int n)
{
    int t = threadIdx.x, b = blockIdx.x;
    int i = b * 256 + t;
    int v = (i < n) ? deg[i] : 0;
    int lane = t & 63, w = t >> 6;
    int x = v;
#pragma unroll
    for (int d = 1; d < 64; d <<= 1) {
        int y = __shfl_up(x, d);
        if (lane >= d) x += y;
    }
    __shared__ int wt[4];
    if (lane == 63) wt[w] = x;
    __syncthreads();
    int woff = 0;
    for (int j = 0; j < 4; j++) if (j < w) woff += wt[j];
    int incl = x + woff;
    if (i < n) partial[i] = incl - v;     // block-local exclusive scan
    if (t == 255) bsum[b] = incl;
}
__global__ void k_scan2(const int* __restrict__ bsum, int* __restrict__ boff, int nb)
{
    int t = threadIdx.x;
    int v = (t < nb) ? bsum[t] : 0;
    int lane = t & 63, w = t >> 6;
    int x = v;
#pragma unroll
    for (int d = 1; d < 64; d <<= 1) {
        int y = __shfl_up(x, d);
        if (lane >= d) x += y;
    }
    __shared__ int wt[4];
    if (lane == 63) wt[w] = x;
    __syncthreads();
    int woff = 0;
    for (int j = 0; j < 4; j++) if (j < w) woff += wt[j];
    boff[t] = (x + woff) - v;             // exclusive scan of block sums
}
__global__ void k_scan3(const int* __restrict__ boff, int* __restrict__ rs,
                        int* __restrict__ cur, int n)
{
    int i = blockIdx.x * 256 + threadIdx.x;
    if (i < n) {
        int v = rs[i] + boff[blockIdx.x];
        rs[i] = v;
        cur[i] = v;
    }
}
__global__ void k_fill(const int* __restrict__ src, const int* __restrict__ dst,
                       const int* __restrict__ et, int* __restrict__ cur,
                       int* __restrict__ sorted, int e)
{
    int i = blockIdx.x * 256 + threadIdx.x;
    if (i < e) {
        int pos = atomicAdd(&cur[dst[i]], 1);
        sorted[pos] = (src[i] << 3) | et[i];   // etype in [0,8)
    }
}

// ---------------------------------------------------------------------------
// Chunked aggregation: one wave per dst node, weight-blocks [b0,b1) this pass.
// flags&1: seed acc with bias; else load accf. flags&2: act+cast+store to out;
// else store accf. Self-loop is global block 8. bias is ws bf16.
// ---------------------------------------------------------------------------
__global__ __launch_bounds__(256) void k_agg2(
    const ushort_t* __restrict__ tb, int ldt,
    const int* __restrict__ rs, const int* __restrict__ deg,
    const int* __restrict__ sorted, const ushort_t* __restrict__ bias,
    float* __restrict__ accf, ushort_t* __restrict__ out,
    int ldo, int col0, int act, int b0, int b1, int flags, int n_nodes)
{
    int w = blockIdx.x * 4 + (threadIdx.x >> 6);
    if (w >= n_nodes) return;
    int lane = threadIdx.x & 63;

    float a0, a1, a2, a3;
    if (flags & 1) {
        a0 = b2f(bias[lane * 4 + 0]);
        a1 = b2f(bias[lane * 4 + 1]);
        a2 = b2f(bias[lane * 4 + 2]);
        a3 = b2f(bias[lane * 4 + 3]);
    } else {
        float4 v = *(const float4*)(accf + (size_t)w * 256 + lane * 4);
        a0 = v.x; a1 = v.y; a2 = v.z; a3 = v.w;
    }
    if (b0 <= 8 && 8 < b1) {                 // self-loop block in this chunk
        ushort4 lv = *(const ushort4*)(tb + (size_t)w * ldt + (8 - b0) * 256 + lane * 4);
        a0 += b2f(lv.x); a1 += b2f(lv.y); a2 += b2f(lv.z); a3 += b2f(lv.w);
    }
    int s = rs[w], cnt = deg[w];
    for (int j = 0; j < cnt; ++j) {
        int p = sorted[s + j];
        int r = p & 7;
        if (r >= b0 && r < b1) {
            const ushort_t* q = tb + (size_t)(p >> 3) * ldt + (r - b0) * 256 + lane * 4;
            ushort4 v = *(const ushort4*)q;
            a0 += b2f(v.x); a1 += b2f(v.y); a2 += b2f(v.z); a3 += b2f(v.w);
        }
    }
    if (flags & 2) {
        if (act) {
            a0 = fmaxf(a0, 0.f); a1 = fmaxf(a1, 0.f);
            a2 = fmaxf(a2, 0.f); a3 = fmaxf(a3, 0.f);
        }
        ushort4 o;
        o.x = f2b(a0); o.y = f2b(a1); o.z = f2b(a2); o.w = f2b(a3);
        *(ushort4*)(out + (size_t)w * ldo + col0 + lane * 4) = o;
    } else {
        *(float4*)(accf + (size_t)w * 256 + lane * 4) = make_float4(a0, a1, a2, a3);
    }
}

// ---------------------------------------------------------------------------
extern "C" void kernel_launch(void* const* d_in, const int* in_sizes, int n_in,
                              void* d_out, int out_size, void* d_ws, size_t ws_size,
                              hipStream_t stream)
{
    const void* poi    = d_in[0];
    const void* timeD  = d_in[1];
    const void* roadF  = d_in[2];
    const void* W_poi  = d_in[3];
    const void* b_poi  = d_in[4];
    const void* W_time = d_in[5];
    const void* b_time = d_in[6];
    const void* W_road = d_in[7];
    const void* b_road = d_in[8];
    // relconv param sets: a1=9..12, a2=13..16, n1=17..20, n2=21..24
    const void* W_fuse  = d_in[25];
    const void* b_fuse  = d_in[26];
    const void* W_fusek = d_in[27];
    const void* b_fusek = d_in[28];
    const int* g_src[2] = {(const int*)d_in[29], (const int*)d_in[32]};
    const int* g_dst[2] = {(const int*)d_in[30], (const int*)d_in[33]};
    const int* g_typ[2] = {(const int*)d_in[31], (const int*)d_in[34]};

    char* p = (char*)d_ws;
    auto alloc = [&](size_t bytes) -> char* {
        char* r = p;
        p += (bytes + 255) & ~(size_t)255;
        return r;
    };
    // ---- fixed allocations (~65 MB) ----
    int*      flags   = (int*)alloc(2 * 4);          // [0]=f32mode, [1]=0
    ushort_t* feat    = (ushort_t*)alloc((size_t)NN * 256 * 2);
    ushort_t* h1      = (ushort_t*)alloc((size_t)NN * 256 * 2);
    ushort_t* fused   = (ushort_t*)alloc((size_t)NN * 512 * 2);
    float*    accf    = (float*)alloc((size_t)NN * 256 * 4);  // also time partials
    ushort_t* wcat    = (ushort_t*)alloc((size_t)NC * 256 * 2);
    ushort_t* wtt     = (ushort_t*)alloc((size_t)128 * TD * 2);
    ushort_t* wft     = (ushort_t*)alloc((size_t)256 * 512 * 2);
    ushort_t* biascat = (ushort_t*)alloc(256 * 2);
    ushort_t* btws    = (ushort_t*)alloc(128 * 2);   // b_time normalized
    ushort_t* biws    = (ushort_t*)alloc(256 * 2);   // per-layer bias normalized
    int* deg    = (int*)alloc((size_t)NN * 4);
    int* rs     = (int*)alloc((size_t)NN * 4);
    int* cur    = (int*)alloc((size_t)NN * 4);
    int* sorted = (int*)alloc((size_t)EE * 4);
    int* bsum   = (int*)alloc(256 * 4);
    int* boff   = (int*)alloc(256 * 4);

    // ---- adaptive tbuf: C weight-blocks (256 cols each) per GEMM pass ----
    size_t used = (size_t)(p - (char*)d_ws);
    size_t per_block = (size_t)NN * 256 * 2;         // 10.24 MB
    int C = 1;
    if (ws_size > used + 512) {
        size_t c = (ws_size - used - 512) / per_block;
        C = (c < 1) ? 1 : (c > 9 ? 9 : (int)c);
    }
    ushort_t* tbuf = (ushort_t*)alloc(per_block * C);
    const int nch = (9 + C - 1) / C;

    const int SB = (NN + 255) / 256;   // 79 scan blocks
    const int EB = (EE + 255) / 256;   // 1250 edge blocks
    const int MT = (NN + 127) / 128;   // 157 m-tiles

    // --- dtype detect, then weight prep ---
    k_detect<<<1, 256, 0, stream>>>(timeD, flags);
    k_transpose<<<TD, 128, 0, stream>>>(W_time, wtt, TD, 128, flags);
    k_build_wfuse<<<512, 256, 0, stream>>>(W_fuse, W_fusek, b_fuse, b_fusek,
                                           wft, biascat, flags);
    k_cvt16<<<1, 256, 0, stream>>>(b_time, btws, 128, flags);

    // --- input feature [NN,256] ---
    k_inproj<<<NN, 128, 0, stream>>>(poi, W_poi, b_poi, roadF, W_road, b_road,
                                     feat, flags);
    // time projection: split-K x6 into f32 partials (accf), then bias+cast
    k_zero<<<(NN * 128 + 255) / 256, 256, 0, stream>>>((int*)accf, NN * 128);
    gemm_splitk<<<dim3(MT, 6), 256, 0, stream>>>(timeD, TD, flags, wtt, TD,
                                                 accf, NN, TD, 480);
    k_bias_time<<<NN, 128, 0, stream>>>(accf, btws, feat);

    // --- two graphs x two R-GCN layers ---
    for (int g = 0; g < 2; ++g) {
        k_zero<<<SB, 256, 0, stream>>>(deg, NN);
        k_count<<<EB, 256, 0, stream>>>(g_dst[g], deg, EE);
        k_scan1<<<SB, 256, 0, stream>>>(deg, rs, bsum, NN);
        k_scan2<<<1, 256, 0, stream>>>(bsum, boff, SB);
        k_scan3<<<SB, 256, 0, stream>>>(boff, rs, cur, NN);
        k_fill<<<EB, 256, 0, stream>>>(g_src[g], g_dst[g], g_typ[g], cur, sorted, EE);

        for (int l = 0; l < 2; ++l) {
            int rc = g * 2 + l;
            const void* cf  = d_in[9 + rc * 4 + 0];
            const void* bs_ = d_in[9 + rc * 4 + 1];
            const void* lw  = d_in[9 + rc * 4 + 2];
            const void* bi  = d_in[9 + rc * 4 + 3];
            k_build_wcat<<<9 * 256, 256, 0, stream>>>(cf, bs_, lw, wcat, flags);
            k_cvt16<<<1, 256, 0, stream>>>(bi, biws, 256, flags);
            const ushort_t* Ain = (l == 0) ? feat : h1;
            ushort_t* dest = (l == 0) ? h1 : fused;
            int ldo  = (l == 0) ? 256 : 512;
            int col0 = (l == 0) ? 0 : g * 256;
            int act  = (l == 0) ? 1 : 0;
            for (int c = 0; c < nch; ++c) {
                int b0 = c * C;
                int b1 = (b0 + C < 9) ? b0 + C : 9;
                int nb = b1 - b0;
                gemm_bt<<<dim3(MT, nb * 2), 256, 0, stream>>>(
                    Ain, 256, wcat + (size_t)b0 * 256 * 256, 256,
                    tbuf, nb * 256, 0, flags + 1, nullptr, NN, nb * 256, 256, 0);
                int fl = (c == 0 ? 1 : 0) | (c == nch - 1 ? 2 : 0);
                k_agg2<<<NN / 4, 256, 0, stream>>>(tbuf, nb * 256, rs, deg, sorted,
                                                   biws, accf, dest, ldo, col0, act,
                                                   b0, b1, fl, NN);
            }
        }
    }

    // --- fusion + exact GELU (output dtype follows input dtype) ---
    gemm_bt<<<dim3(MT, 2), 256, 0, stream>>>(fused, 512, wft, 512,
                                             d_out, 256, 0, flags, biascat,
                                             NN, 256, 512, 2);
}

// Round 4
// 1088.298 us; speedup vs baseline: 1.0431x; 1.0180x over previous
//
#include <hip/hip_runtime.h>
#include <math.h>

typedef unsigned short ushort_t;                       // bf16 bit storage
typedef __bf16 bf16x8 __attribute__((ext_vector_type(8)));
typedef float  f32x4  __attribute__((ext_vector_type(4)));

constexpr int NN = 20000;   // nodes
constexpr int EE = 320000;  // edges
constexpr int NC = 2304;    // 9*256 projection width (8 rels + self-loop)
constexpr int TD = 2880;    // time dim

__device__ __forceinline__ float b2f(ushort_t u) {
    return __uint_as_float(((unsigned int)u) << 16);
}
__device__ __forceinline__ ushort_t f2b(float f) {
    unsigned int u = __float_as_uint(f);
    u += 0x7fffu + ((u >> 16) & 1u);                   // round-to-nearest-even
    return (ushort_t)(u >> 16);
}
// dual-dtype load: raw inputs may be f32 or bf16 (runtime-detected flag)
__device__ __forceinline__ float ldf(const void* p, size_t i, int f32m) {
    return f32m ? ((const float*)p)[i] : b2f(((const ushort_t*)p)[i]);
}
// async global->LDS, 16B per lane; LDS dest = wave-uniform base + lane*16
__device__ __forceinline__ void gl2lds16(const ushort_t* g, ushort_t* l) {
    __builtin_amdgcn_global_load_lds(
        (const __attribute__((address_space(1))) void*)g,
        (__attribute__((address_space(3))) void*)l, 16, 0, 0);
}

// shared MFMA inner step: LDS tiles [128 rows x 32 k] -> 4x4 acc of 16x16x32
__device__ __forceinline__ void mfma_step(const ushort_t* As, const ushort_t* Bs,
                                          f32x4 (&acc)[4][4],
                                          int wm, int wn, int quad, int l16)
{
    bf16x8 afr[4], bfr[4];
#pragma unroll
    for (int mi = 0; mi < 4; mi++)
        afr[mi] = *(const bf16x8*)(As + (wm * 64 + mi * 16 + l16) * 32 + quad * 8);
#pragma unroll
    for (int ni = 0; ni < 4; ni++)
        bfr[ni] = *(const bf16x8*)(Bs + (wn * 64 + ni * 16 + l16) * 32 + quad * 8);
#pragma unroll
    for (int mi = 0; mi < 4; mi++)
#pragma unroll
        for (int ni = 0; ni < 4; ni++)
            acc[mi][ni] = __builtin_amdgcn_mfma_f32_16x16x32_bf16(
                afr[mi], bfr[ni], acc[mi][ni], 0, 0, 0);
}

// ---------------------------------------------------------------------------
// Detect input dtype (bf16-stored vs f32-stored). flags[0]=f32mode, flags[1]=0.
// ---------------------------------------------------------------------------
__global__ void k_detect(const void* timeD, int* flags)
{
    __shared__ float mx[256];
    int t = threadIdx.x;
    float m = 0.f;
    for (int i = t; i < 1024; i += 256) {
        float v = fabsf(b2f(((const ushort_t*)timeD)[i]));
        if (!(v < 1e30f)) v = 1e30f;   // NaN/Inf -> huge
        m = fmaxf(m, v);
    }
    mx[t] = m;
    __syncthreads();
    if (t == 0) {
        float mm = 0.f;
        for (int i = 0; i < 256; i++) mm = fmaxf(mm, mx[i]);
        flags[0] = (mm > 1e4f) ? 1 : 0;
        flags[1] = 0;
    }
}

// small dtype-normalizing copy: out (bf16) <- in (f32 or bf16)
__global__ void k_cvt16(const void* __restrict__ in, ushort_t* __restrict__ out,
                        int n, const int* __restrict__ mf)
{
    int f32m = mf[0];
    int i = blockIdx.x * 256 + threadIdx.x;
    if (i < n) out[i] = f32m ? f2b(((const float*)in)[i]) : ((const ushort_t*)in)[i];
}

// ---------------------------------------------------------------------------
// Main bf16 MFMA GEMM (A is a ws bf16 buffer): C = act(A * Bt^T + bias).
// global_load_lds width-16 staging; LDS row stride 32 shorts (64B) so the
// lane->LDS map is linear (wave-uniform base + lane*16). 2-way bank alias on
// ds_read_b128 is free (m136). Tile 128x128, BK=32, 4 waves (2x2).
// A rows may over-read past M (stays inside d_ws; epilogue masks stores).
// Ncols must be a multiple of 128 (true for 2304/256).
// ---------------------------------------------------------------------------
__global__ __launch_bounds__(256) void gemm_bt(
    const ushort_t* __restrict__ A, int lda,
    const ushort_t* __restrict__ Bt, int ldb,
    void* __restrict__ C, int ldc, int col0, const int* __restrict__ of,
    const ushort_t* __restrict__ bias,
    int M, int Ncols, int K, int act)
{
    __shared__ ushort_t As[128 * 32];
    __shared__ ushort_t Bs[128 * 32];

    const int f32o = of[0];
    const int t    = threadIdx.x;
    const int wave = t >> 6, lane = t & 63;
    const int wm   = wave >> 1, wn = wave & 1;
    const int quad = lane >> 4, l16 = lane & 15;
    const int m0   = blockIdx.x * 128, n0 = blockIdx.y * 128;

    f32x4 acc[4][4];
#pragma unroll
    for (int i = 0; i < 4; i++)
#pragma unroll
        for (int j = 0; j < 4; j++) acc[i][j] = (f32x4){0.f, 0.f, 0.f, 0.f};

    for (int k0 = 0; k0 < K; k0 += 32) {
#pragma unroll
        for (int j = 0; j < 2; j++) {
            int c   = (wave * 2 + j) * 64 + lane;     // 16B chunk id, 512 total
            int row = c >> 2, kc = c & 3;
            ushort_t* ldsbase_a = As + (wave * 2 + j) * 512;  // wave-uniform
            ushort_t* ldsbase_b = Bs + (wave * 2 + j) * 512;
            gl2lds16(A  + (size_t)(m0 + row) * lda + k0 + kc * 8, ldsbase_a);
            gl2lds16(Bt + (size_t)(n0 + row) * ldb + k0 + kc * 8, ldsbase_b);
        }
        __syncthreads();
        mfma_step(As, Bs, acc, wm, wn, quad, l16);
        __syncthreads();
    }

#pragma unroll
    for (int mi = 0; mi < 4; mi++) {
#pragma unroll
        for (int r = 0; r < 4; r++) {
            int row = m0 + wm * 64 + mi * 16 + quad * 4 + r;
            if (row >= M) continue;
#pragma unroll
            for (int ni = 0; ni < 4; ni++) {
                int col = n0 + wn * 64 + ni * 16 + l16;
                float v = acc[mi][ni][r];
                if (bias) v += b2f(bias[col]);
                if (act == 1) v = fmaxf(v, 0.f);
                else if (act == 2) v = 0.5f * v * (1.f + erff(v * 0.70710678118654752f));
                size_t idx = (size_t)row * ldc + col0 + col;
                if (f32o) ((float*)C)[idx] = v;
                else      ((ushort_t*)C)[idx] = f2b(v);
            }
        }
    }
}

// ---------------------------------------------------------------------------
// Split-K GEMM for the time projection (A raw f32 or bf16, N=128 fixed).
// grid (m_tiles, nsplit); each split writes its PRIVATE f32 partial slice
// part[split][M][128] with plain coalesced stores (NO atomics -- the round-0
// profile showed the atomic epilogue was the throughput limit: 20.5M RMW
// ops ~ 131G/s ceiling). A reduce kernel sums the slices afterwards.
// bf16 + full m-tile: async global_load_lds staging (proven gemm_bt pattern).
// Otherwise (f32 input, or the single partial last tile): dual-dtype VGPR
// staging with guarded rows, zero-fill.
// ---------------------------------------------------------------------------
__global__ __launch_bounds__(256) void gemm_splitk(
    const void* __restrict__ A, int lda, const int* __restrict__ af,
    const ushort_t* __restrict__ Bt, int ldb,
    float* __restrict__ part, int M, int K, int KC)
{
    __shared__ ushort_t As[128 * 32];
    __shared__ ushort_t Bs[128 * 32];

    const int f32a = af[0];
    const int t    = threadIdx.x;
    const int wave = t >> 6, lane = t & 63;
    const int wm   = wave >> 1, wn = wave & 1;
    const int quad = lane >> 4, l16 = lane & 15;
    const int m0   = blockIdx.x * 128;
    const int kbeg = blockIdx.y * KC;
    const int kend = (kbeg + KC < K) ? kbeg + KC : K;

    f32x4 acc[4][4];
#pragma unroll
    for (int i = 0; i < 4; i++)
#pragma unroll
        for (int j = 0; j < 4; j++) acc[i][j] = (f32x4){0.f, 0.f, 0.f, 0.f};

    if (!f32a && (m0 + 128 <= M)) {
        // ---- bf16 full-tile fast path: async DMA staging (no guards) ----
        const ushort_t* Ab = (const ushort_t*)A;
        for (int k0 = kbeg; k0 < kend; k0 += 32) {
#pragma unroll
            for (int j = 0; j < 2; j++) {
                int c   = (wave * 2 + j) * 64 + lane;
                int row = c >> 2, kc = c & 3;
                gl2lds16(Ab + (size_t)(m0 + row) * lda + k0 + kc * 8,
                         As + (wave * 2 + j) * 512);
                gl2lds16(Bt + (size_t)row * ldb + k0 + kc * 8,
                         Bs + (wave * 2 + j) * 512);
            }
            __syncthreads();
            mfma_step(As, Bs, acc, wm, wn, quad, l16);
            __syncthreads();
        }
    } else {
        // ---- dual-dtype VGPR staging (guarded rows, zero-fill) ----
        for (int k0 = kbeg; k0 < kend; k0 += 32) {
#pragma unroll
            for (int i = 0; i < 2; i++) {
                int c = t + i * 256;              // 512 chunks of 8 elements
                int row = c >> 2, kc = c & 3;
                uint4 av = make_uint4(0, 0, 0, 0);
                int gr = m0 + row;
                if (gr < M) {
                    size_t base = (size_t)gr * lda + k0 + kc * 8;
                    if (f32a) {
                        const float* Af = (const float*)A + base;
                        float4 lo = *(const float4*)Af;
                        float4 hi = *(const float4*)(Af + 4);
                        av.x = (unsigned)f2b(lo.x) | ((unsigned)f2b(lo.y) << 16);
                        av.y = (unsigned)f2b(lo.z) | ((unsigned)f2b(lo.w) << 16);
                        av.z = (unsigned)f2b(hi.x) | ((unsigned)f2b(hi.y) << 16);
                        av.w = (unsigned)f2b(hi.z) | ((unsigned)f2b(hi.w) << 16);
                    } else {
                        av = *(const uint4*)((const ushort_t*)A + base);
                    }
                }
                *(uint4*)(As + row * 32 + kc * 8) = av;
                uint4 bv = *(const uint4*)(Bt + (size_t)row * ldb + k0 + kc * 8);
                *(uint4*)(Bs + row * 32 + kc * 8) = bv;
            }
            __syncthreads();
            mfma_step(As, Bs, acc, wm, wn, quad, l16);
            __syncthreads();
        }
    }

    // plain stores into this split's private slice (no atomics)
    float* dst = part + (size_t)blockIdx.y * ((size_t)M * 128);
#pragma unroll
    for (int mi = 0; mi < 4; mi++) {
#pragma unroll
        for (int r = 0; r < 4; r++) {
            int row = m0 + wm * 64 + mi * 16 + quad * 4 + r;
            if (row >= M) continue;
#pragma unroll
            for (int ni = 0; ni < 4; ni++) {
                int col = wn * 64 + ni * 16 + l16;
                dst[(size_t)row * 128 + col] = acc[mi][ni][r];
            }
        }
    }
}

// feat cols 64..191 <- sum_s part[s] + b_time; grid NN, 128 threads
__global__ void k_bias_time(const float* __restrict__ part, int nsplit,
                            const ushort_t* __restrict__ bt,
                            ushort_t* __restrict__ feat)
{
    int n = blockIdx.x, o = threadIdx.x;
    float a = b2f(bt[o]);
    for (int s = 0; s < nsplit; ++s)
        a += part[(size_t)s * NN * 128 + (size_t)n * 128 + o];
    feat[(size_t)n * 256 + 64 + o] = f2b(a);
}

// ---------------------------------------------------------------------------
// Build Wcat_t [2304(=9*256), 256]: row r*256+o holds column o of W_r over k.
// r<8: W_r = sum_b coeff[r,b]*bases[b];  r==8: self-loop weight.
// ---------------------------------------------------------------------------
__global__ void k_build_wcat(const void* __restrict__ coeff,
                             const void* __restrict__ bases,
                             const void* __restrict__ loopw,
                             ushort_t* __restrict__ Wt, const int* __restrict__ mf)
{
    int f32m = mf[0];
    int r = blockIdx.x >> 8, k = blockIdx.x & 255, o = threadIdx.x;
    float acc;
    if (r == 8) {
        acc = ldf(loopw, k * 256 + o, f32m);
    } else {
        acc = 0.f;
#pragma unroll
        for (int b = 0; b < 8; b++)
            acc += ldf(coeff, r * 8 + b, f32m) * ldf(bases, ((size_t)b * 256 + k) * 256 + o, f32m);
    }
    Wt[((size_t)(r * 256 + o)) * 256 + k] = f2b(acc);
}

// transpose raw [rows,cols] -> ws bf16 [cols,rows]
__global__ void k_transpose(const void* __restrict__ in, ushort_t* __restrict__ out,
                            int rows, int cols, const int* __restrict__ mf)
{
    int f32m = mf[0];
    int k = blockIdx.x, o = threadIdx.x;
    out[(size_t)o * rows + k] = f2b(ldf(in, (size_t)k * cols + o, f32m));
}

// Wfuse_t [256, 512] + bias_cat[o] = b_fuse[o] + b_fuse_kg[o]
__global__ void k_build_wfuse(const void* __restrict__ Wf, const void* __restrict__ Wfk,
                              const void* __restrict__ bf, const void* __restrict__ bfk,
                              ushort_t* __restrict__ Wt, ushort_t* __restrict__ bias_cat,
                              const int* __restrict__ mf)
{
    int f32m = mf[0];
    int k = blockIdx.x, o = threadIdx.x;
    float v = (k < 256) ? ldf(Wf, k * 256 + o, f32m) : ldf(Wfk, (k - 256) * 256 + o, f32m);
    Wt[(size_t)o * 512 + k] = f2b(v);
    if (k == 0) bias_cat[o] = f2b(ldf(bf, o, f32m) + ldf(bfk, o, f32m));
}

// poi (64 cols @0) + road (64 cols @192) projections; grid NN, 128 threads
__global__ void k_inproj(const void* __restrict__ poi, const void* __restrict__ Wp,
                         const void* __restrict__ bp,
                         const void* __restrict__ road, const void* __restrict__ Wr,
                         const void* __restrict__ br,
                         ushort_t* __restrict__ feat, const int* __restrict__ mf)
{
    int f32m = mf[0];
    int n = blockIdx.x, t = threadIdx.x;
    if (t < 64) {
        float a = ldf(bp, t, f32m);
#pragma unroll
        for (int k = 0; k < 12; k++)
            a += ldf(poi, (size_t)n * 12 + k, f32m) * ldf(Wp, k * 64 + t, f32m);
        feat[(size_t)n * 256 + t] = f2b(a);
    } else {
        int o = t - 64;
        float a = ldf(br, o, f32m);
#pragma unroll
        for (int k = 0; k < 32; k++)
            a += ldf(road, (size_t)n * 32 + k, f32m) * ldf(Wr, k * 64 + o, f32m);
        feat[(size_t)n * 256 + 192 + o] = f2b(a);
    }
}

// ------------------------- CSR build (per graph) ---------------------------
__global__ void k_zero(int* __restrict__ p, int n)
{
    int i = blockIdx.x * 256 + threadIdx.x;
    if (i < n) p[i] = 0;
}
__global__ void k_count(const int* __restrict__ dst, int* __restrict__ deg, int e)
{
    int i = blockIdx.x * 256 + threadIdx.x;
    if (i < e) atomicAdd(&deg[dst[i]], 1);
}
__global__ void k_scan1(const int* __restrict__ deg, int* __restrict__ partial,
                        int* __restrict__ bsum, int n)
{
    int t = threadIdx.x, b = blockIdx.x;
    int i = b * 256 + t;
    int v = (i < n) ? deg[i] : 0;
    int lane = t & 63, w = t >> 6;
    int x = v;
#pragma unroll
    for (int d = 1; d < 64; d <<= 1) {
        int y = __shfl_up(x, d);
        if (lane >= d) x += y;
    }
    __shared__ int wt[4];
    if (lane == 63) wt[w] = x;
    __syncthreads();
    int woff = 0;
    for (int j = 0; j < 4; j++) if (j < w) woff += wt[j];
    int incl = x + woff;
    if (i < n) partial[i] = incl - v;     // block-local exclusive scan
    if (t == 255) bsum[b] = incl;
}
__global__ void k_scan2(const int* __restrict__ bsum, int* __restrict__ boff, int nb)
{
    int t = threadIdx.x;
    int v = (t < nb) ? bsum[t] : 0;
    int lane = t & 63, w = t >> 6;
    int x = v;
#pragma unroll
    for (int d = 1; d < 64; d <<= 1) {
        int y = __shfl_up(x, d);
        if (lane >= d) x += y;
    }
    __shared__ int wt[4];
    if (lane == 63) wt[w] = x;
    __syncthreads();
    int woff = 0;
    for (int j = 0; j < 4; j++) if (j < w) woff += wt[j];
    boff[t] = (x + woff) - v;             // exclusive scan of block sums
}
__global__ void k_scan3(const int* __restrict__ boff, int* __restrict__ rs,
                        int* __restrict__ cur, int n)
{
    int i = blockIdx.x * 256 + threadIdx.x;
    if (i < n) {
        int v = rs[i] + boff[blockIdx.x];
        rs[i] = v;
        cur[i] = v;
    }
}
__global__ void k_fill(const int* __restrict__ src, const int* __restrict__ dst,
                       const int* __restrict__ et, int* __restrict__ cur,
                       int* __restrict__ sorted, int e)
{
    int i = blockIdx.x * 256 + threadIdx.x;
    if (i < e) {
        int pos = atomicAdd(&cur[dst[i]], 1);
        sorted[pos] = (src[i] << 3) | et[i];   // etype in [0,8)
    }
}

// ---------------------------------------------------------------------------
// Chunked aggregation: one wave per dst node, weight-blocks [b0,b1) this pass.
// flags&1: seed acc with bias; else load accf. flags&2: act+cast+store to out;
// else store accf. Self-loop is global block 8. bias is ws bf16.
// ---------------------------------------------------------------------------
__global__ __launch_bounds__(256) void k_agg2(
    const ushort_t* __restrict__ tb, int ldt,
    const int* __restrict__ rs, const int* __restrict__ deg,
    const int* __restrict__ sorted, const ushort_t* __restrict__ bias,
    float* __restrict__ accf, ushort_t* __restrict__ out,
    int ldo, int col0, int act, int b0, int b1, int flags, int n_nodes)
{
    int w = blockIdx.x * 4 + (threadIdx.x >> 6);
    if (w >= n_nodes) return;
    int lane = threadIdx.x & 63;

    float a0, a1, a2, a3;
    if (flags & 1) {
        a0 = b2f(bias[lane * 4 + 0]);
        a1 = b2f(bias[lane * 4 + 1]);
        a2 = b2f(bias[lane * 4 + 2]);
        a3 = b2f(bias[lane * 4 + 3]);
    } else {
        float4 v = *(const float4*)(accf + (size_t)w * 256 + lane * 4);
        a0 = v.x; a1 = v.y; a2 = v.z; a3 = v.w;
    }
    if (b0 <= 8 && 8 < b1) {                 // self-loop block in this chunk
        ushort4 lv = *(const ushort4*)(tb + (size_t)w * ldt + (8 - b0) * 256 + lane * 4);
        a0 += b2f(lv.x); a1 += b2f(lv.y); a2 += b2f(lv.z); a3 += b2f(lv.w);
    }
    int s = rs[w], cnt = deg[w];
    for (int j = 0; j < cnt; ++j) {
        int p = sorted[s + j];
        int r = p & 7;
        if (r >= b0 && r < b1) {
            const ushort_t* q = tb + (size_t)(p >> 3) * ldt + (r - b0) * 256 + lane * 4;
            ushort4 v = *(const ushort4*)q;
            a0 += b2f(v.x); a1 += b2f(v.y); a2 += b2f(v.z); a3 += b2f(v.w);
        }
    }
    if (flags & 2) {
        if (act) {
            a0 = fmaxf(a0, 0.f); a1 = fmaxf(a1, 0.f);
            a2 = fmaxf(a2, 0.f); a3 = fmaxf(a3, 0.f);
        }
        ushort4 o;
        o.x = f2b(a0); o.y = f2b(a1); o.z = f2b(a2); o.w = f2b(a3);
        *(ushort4*)(out + (size_t)w * ldo + col0 + lane * 4) = o;
    } else {
        *(float4*)(accf + (size_t)w * 256 + lane * 4) = make_float4(a0, a1, a2, a3);
    }
}

// ---------------------------------------------------------------------------
extern "C" void kernel_launch(void* const* d_in, const int* in_sizes, int n_in,
                              void* d_out, int out_size, void* d_ws, size_t ws_size,
                              hipStream_t stream)
{
    const void* poi    = d_in[0];
    const void* timeD  = d_in[1];
    const void* roadF  = d_in[2];
    const void* W_poi  = d_in[3];
    const void* b_poi  = d_in[4];
    const void* W_time = d_in[5];
    const void* b_time = d_in[6];
    const void* W_road = d_in[7];
    const void* b_road = d_in[8];
    // relconv param sets: a1=9..12, a2=13..16, n1=17..20, n2=21..24
    const void* W_fuse  = d_in[25];
    const void* b_fuse  = d_in[26];
    const void* W_fusek = d_in[27];
    const void* b_fusek = d_in[28];
    const int* g_src[2] = {(const int*)d_in[29], (const int*)d_in[32]};
    const int* g_dst[2] = {(const int*)d_in[30], (const int*)d_in[33]};
    const int* g_typ[2] = {(const int*)d_in[31], (const int*)d_in[34]};

    char* p = (char*)d_ws;
    auto alloc = [&](size_t bytes) -> char* {
        char* r = p;
        p += (bytes + 255) & ~(size_t)255;
        return r;
    };
    // ---- fixed allocations (~65 MB) ----
    int*      flags   = (int*)alloc(2 * 4);          // [0]=f32mode, [1]=0
    ushort_t* feat    = (ushort_t*)alloc((size_t)NN * 256 * 2);
    ushort_t* h1      = (ushort_t*)alloc((size_t)NN * 256 * 2);
    ushort_t* fused   = (ushort_t*)alloc((size_t)NN * 512 * 2);
    float*    accf    = (float*)alloc((size_t)NN * 256 * 4);  // rgcn chunk accum
    ushort_t* wcat    = (ushort_t*)alloc((size_t)NC * 256 * 2);
    ushort_t* wtt     = (ushort_t*)alloc((size_t)128 * TD * 2);
    ushort_t* wft     = (ushort_t*)alloc((size_t)256 * 512 * 2);
    ushort_t* biascat = (ushort_t*)alloc(256 * 2);
    ushort_t* btws    = (ushort_t*)alloc(128 * 2);   // b_time normalized
    ushort_t* biws    = (ushort_t*)alloc(256 * 2);   // per-layer bias normalized
    int* deg    = (int*)alloc((size_t)NN * 4);
    int* rs     = (int*)alloc((size_t)NN * 4);
    int* cur    = (int*)alloc((size_t)NN * 4);
    int* sorted = (int*)alloc((size_t)EE * 4);
    int* bsum   = (int*)alloc(256 * 4);
    int* boff   = (int*)alloc(256 * 4);

    // ---- adaptive split-K partial slices (no atomics) ----
    size_t psl       = (size_t)NN * 128 * 4;         // one slice: 10.24 MB
    size_t per_block = (size_t)NN * 256 * 2;         // tbuf block: 10.24 MB
    size_t used0 = (size_t)(p - (char*)d_ws);
    int SPLITS;
    float* tpart;
    if (ws_size > used0 + per_block + 512 + psl) {
        size_t s = (ws_size - used0 - per_block - 512) / psl;
        SPLITS = (int)(s > 6 ? 6 : s);
        tpart  = (float*)alloc(psl * SPLITS);
    } else {
        tpart  = accf;                                // accf holds 2 slices
        SPLITS = 2;
    }
    const int KC = TD / SPLITS;                       // all of 1..6 divide 2880

    // ---- adaptive tbuf: C weight-blocks (256 cols each) per GEMM pass ----
    size_t used = (size_t)(p - (char*)d_ws);
    int C = 1;
    if (ws_size > used + 512) {
        size_t c = (ws_size - used - 512) / per_block;
        C = (c < 1) ? 1 : (c > 9 ? 9 : (int)c);
    }
    ushort_t* tbuf = (ushort_t*)alloc(per_block * C);
    const int nch = (9 + C - 1) / C;

    const int SB = (NN + 255) / 256;   // 79 scan blocks
    const int EB = (EE + 255) / 256;   // 1250 edge blocks
    const int MT = (NN + 127) / 128;   // 157 m-tiles

    // --- dtype detect, then weight prep ---
    k_detect<<<1, 256, 0, stream>>>(timeD, flags);
    k_transpose<<<TD, 128, 0, stream>>>(W_time, wtt, TD, 128, flags);
    k_build_wfuse<<<512, 256, 0, stream>>>(W_fuse, W_fusek, b_fuse, b_fusek,
                                           wft, biascat, flags);
    k_cvt16<<<1, 256, 0, stream>>>(b_time, btws, 128, flags);

    // --- input feature [NN,256] ---
    k_inproj<<<NN, 128, 0, stream>>>(poi, W_poi, b_poi, roadF, W_road, b_road,
                                     feat, flags);
    // time projection: split-K into private f32 slices, then reduce+bias+cast
    gemm_splitk<<<dim3(MT, SPLITS), 256, 0, stream>>>(timeD, TD, flags, wtt, TD,
                                                      tpart, NN, TD, KC);
    k_bias_time<<<NN, 128, 0, stream>>>(tpart, SPLITS, btws, feat);

    // --- two graphs x two R-GCN layers ---
    for (int g = 0; g < 2; ++g) {
        k_zero<<<SB, 256, 0, stream>>>(deg, NN);
        k_count<<<EB, 256, 0, stream>>>(g_dst[g], deg, EE);
        k_scan1<<<SB, 256, 0, stream>>>(deg, rs, bsum, NN);
        k_scan2<<<1, 256, 0, stream>>>(bsum, boff, SB);
        k_scan3<<<SB, 256, 0, stream>>>(boff, rs, cur, NN);
        k_fill<<<EB, 256, 0, stream>>>(g_src[g], g_dst[g], g_typ[g], cur, sorted, EE);

        for (int l = 0; l < 2; ++l) {
            int rc = g * 2 + l;
            const void* cf  = d_in[9 + rc * 4 + 0];
            const void* bs_ = d_in[9 + rc * 4 + 1];
            const void* lw  = d_in[9 + rc * 4 + 2];
            const void* bi  = d_in[9 + rc * 4 + 3];
            k_build_wcat<<<9 * 256, 256, 0, stream>>>(cf, bs_, lw, wcat, flags);
            k_cvt16<<<1, 256, 0, stream>>>(bi, biws, 256, flags);
            const ushort_t* Ain = (l == 0) ? feat : h1;
            ushort_t* dest = (l == 0) ? h1 : fused;
            int ldo  = (l == 0) ? 256 : 512;
            int col0 = (l == 0) ? 0 : g * 256;
            int act  = (l == 0) ? 1 : 0;
            for (int c = 0; c < nch; ++c) {
                int b0 = c * C;
                int b1 = (b0 + C < 9) ? b0 + C : 9;
                int nb = b1 - b0;
                gemm_bt<<<dim3(MT, nb * 2), 256, 0, stream>>>(
                    Ain, 256, wcat + (size_t)b0 * 256 * 256, 256,
                    tbuf, nb * 256, 0, flags + 1, nullptr, NN, nb * 256, 256, 0);
                int fl = (c == 0 ? 1 : 0) | (c == nch - 1 ? 2 : 0);
                k_agg2<<<NN / 4, 256, 0, stream>>>(tbuf, nb * 256, rs, deg, sorted,
                                                   biws, accf, dest, ldo, col0, act,
                                                   b0, b1, fl, NN);
            }
        }
    }

    // --- fusion + exact GELU (output dtype follows input dtype) ---
    gemm_bt<<<dim3(MT, 2), 256, 0, stream>>>(fused, 512, wft, 512,
                                             d_out, 256, 0, flags, biascat,
                                             NN, 256, 512, 2);
}

// Round 5
// 1009.205 us; speedup vs baseline: 1.1249x; 1.0784x over previous
//
#include <hip/hip_runtime.h>
#include <math.h>

typedef unsigned short ushort_t;                       // bf16 bit storage
typedef __bf16 bf16x8 __attribute__((ext_vector_type(8)));
typedef float  f32x4  __attribute__((ext_vector_type(4)));

constexpr int NN = 20000;   // nodes
constexpr int EE = 320000;  // edges
constexpr int NC = 2304;    // 9*256 projection width (8 rels + self-loop)
constexpr int TD = 2880;    // time dim

__device__ __forceinline__ float b2f(ushort_t u) {
    return __uint_as_float(((unsigned int)u) << 16);
}
__device__ __forceinline__ ushort_t f2b(float f) {
    unsigned int u = __float_as_uint(f);
    u += 0x7fffu + ((u >> 16) & 1u);                   // round-to-nearest-even
    return (ushort_t)(u >> 16);
}
// dual-dtype load: raw inputs may be f32 or bf16 (runtime-detected flag)
__device__ __forceinline__ float ldf(const void* p, size_t i, int f32m) {
    return f32m ? ((const float*)p)[i] : b2f(((const ushort_t*)p)[i]);
}
// async global->LDS, 16B per lane; LDS dest = wave-uniform base + lane*16
__device__ __forceinline__ void gl2lds16(const ushort_t* g, ushort_t* l) {
    __builtin_amdgcn_global_load_lds(
        (const __attribute__((address_space(1))) void*)g,
        (__attribute__((address_space(3))) void*)l, 16, 0, 0);
}

// shared MFMA inner step: LDS tiles [128 rows x 32 k] -> 4x4 acc of 16x16x32
__device__ __forceinline__ void mfma_step(const ushort_t* As, const ushort_t* Bs,
                                          f32x4 (&acc)[4][4],
                                          int wm, int wn, int quad, int l16)
{
    bf16x8 afr[4], bfr[4];
#pragma unroll
    for (int mi = 0; mi < 4; mi++)
        afr[mi] = *(const bf16x8*)(As + (wm * 64 + mi * 16 + l16) * 32 + quad * 8);
#pragma unroll
    for (int ni = 0; ni < 4; ni++)
        bfr[ni] = *(const bf16x8*)(Bs + (wn * 64 + ni * 16 + l16) * 32 + quad * 8);
#pragma unroll
    for (int mi = 0; mi < 4; mi++)
#pragma unroll
        for (int ni = 0; ni < 4; ni++)
            acc[mi][ni] = __builtin_amdgcn_mfma_f32_16x16x32_bf16(
                afr[mi], bfr[ni], acc[mi][ni], 0, 0, 0);
}

// ---------------------------------------------------------------------------
// Detect input dtype (bf16-stored vs f32-stored). flags[0]=f32mode, flags[1]=0.
// ---------------------------------------------------------------------------
__global__ void k_detect(const void* timeD, int* flags)
{
    __shared__ float mx[256];
    int t = threadIdx.x;
    float m = 0.f;
    for (int i = t; i < 1024; i += 256) {
        float v = fabsf(b2f(((const ushort_t*)timeD)[i]));
        if (!(v < 1e30f)) v = 1e30f;   // NaN/Inf -> huge
        m = fmaxf(m, v);
    }
    mx[t] = m;
    __syncthreads();
    if (t == 0) {
        float mm = 0.f;
        for (int i = 0; i < 256; i++) mm = fmaxf(mm, mx[i]);
        flags[0] = (mm > 1e4f) ? 1 : 0;
        flags[1] = 0;
    }
}

// small dtype-normalizing copy: out (bf16) <- in (f32 or bf16)
__global__ void k_cvt16(const void* __restrict__ in, ushort_t* __restrict__ out,
                        int n, const int* __restrict__ mf)
{
    int f32m = mf[0];
    int i = blockIdx.x * 256 + threadIdx.x;
    if (i < n) out[i] = f32m ? f2b(((const float*)in)[i]) : ((const ushort_t*)in)[i];
}

// ---------------------------------------------------------------------------
// Main bf16 MFMA GEMM (A is a ws bf16 buffer): C = act(A * Bt^T + bias).
// global_load_lds width-16 staging; LDS row stride 32 shorts (64B) so the
// lane->LDS map is linear (wave-uniform base + lane*16). 2-way bank alias on
// ds_read_b128 is free (m136). Tile 128x128, BK=32, 4 waves (2x2).
// A rows may over-read past M (stays inside d_ws; epilogue masks stores).
// Ncols must be a multiple of 128 (true for 2304/256).
// ---------------------------------------------------------------------------
__global__ __launch_bounds__(256) void gemm_bt(
    const ushort_t* __restrict__ A, int lda,
    const ushort_t* __restrict__ Bt, int ldb,
    void* __restrict__ C, int ldc, int col0, const int* __restrict__ of,
    const ushort_t* __restrict__ bias,
    int M, int Ncols, int K, int act)
{
    __shared__ ushort_t As[128 * 32];
    __shared__ ushort_t Bs[128 * 32];

    const int f32o = of[0];
    const int t    = threadIdx.x;
    const int wave = t >> 6, lane = t & 63;
    const int wm   = wave >> 1, wn = wave & 1;
    const int quad = lane >> 4, l16 = lane & 15;
    const int m0   = blockIdx.x * 128, n0 = blockIdx.y * 128;

    f32x4 acc[4][4];
#pragma unroll
    for (int i = 0; i < 4; i++)
#pragma unroll
        for (int j = 0; j < 4; j++) acc[i][j] = (f32x4){0.f, 0.f, 0.f, 0.f};

    for (int k0 = 0; k0 < K; k0 += 32) {
#pragma unroll
        for (int j = 0; j < 2; j++) {
            int c   = (wave * 2 + j) * 64 + lane;     // 16B chunk id, 512 total
            int row = c >> 2, kc = c & 3;
            ushort_t* ldsbase_a = As + (wave * 2 + j) * 512;  // wave-uniform
            ushort_t* ldsbase_b = Bs + (wave * 2 + j) * 512;
            gl2lds16(A  + (size_t)(m0 + row) * lda + k0 + kc * 8, ldsbase_a);
            gl2lds16(Bt + (size_t)(n0 + row) * ldb + k0 + kc * 8, ldsbase_b);
        }
        __syncthreads();
        mfma_step(As, Bs, acc, wm, wn, quad, l16);
        __syncthreads();
    }

#pragma unroll
    for (int mi = 0; mi < 4; mi++) {
#pragma unroll
        for (int r = 0; r < 4; r++) {
            int row = m0 + wm * 64 + mi * 16 + quad * 4 + r;
            if (row >= M) continue;
#pragma unroll
            for (int ni = 0; ni < 4; ni++) {
                int col = n0 + wn * 64 + ni * 16 + l16;
                float v = acc[mi][ni][r];
                if (bias) v += b2f(bias[col]);
                if (act == 1) v = fmaxf(v, 0.f);
                else if (act == 2) v = 0.5f * v * (1.f + erff(v * 0.70710678118654752f));
                size_t idx = (size_t)row * ldc + col0 + col;
                if (f32o) ((float*)C)[idx] = v;
                else      ((ushort_t*)C)[idx] = f2b(v);
            }
        }
    }
}

// ---------------------------------------------------------------------------
// Split-K GEMM for the time projection (A raw f32 or bf16, N=128 fixed).
// grid (m_tiles, nsplit); each split writes its PRIVATE f32 partial slice
// part[split][M][128] with plain coalesced stores (no atomics). A reduce
// kernel sums the slices afterwards.
// ---------------------------------------------------------------------------
__global__ __launch_bounds__(256) void gemm_splitk(
    const void* __restrict__ A, int lda, const int* __restrict__ af,
    const ushort_t* __restrict__ Bt, int ldb,
    float* __restrict__ part, int M, int K, int KC)
{
    __shared__ ushort_t As[128 * 32];
    __shared__ ushort_t Bs[128 * 32];

    const int f32a = af[0];
    const int t    = threadIdx.x;
    const int wave = t >> 6, lane = t & 63;
    const int wm   = wave >> 1, wn = wave & 1;
    const int quad = lane >> 4, l16 = lane & 15;
    const int m0   = blockIdx.x * 128;
    const int kbeg = blockIdx.y * KC;
    const int kend = (kbeg + KC < K) ? kbeg + KC : K;

    f32x4 acc[4][4];
#pragma unroll
    for (int i = 0; i < 4; i++)
#pragma unroll
        for (int j = 0; j < 4; j++) acc[i][j] = (f32x4){0.f, 0.f, 0.f, 0.f};

    if (!f32a && (m0 + 128 <= M)) {
        // ---- bf16 full-tile fast path: async DMA staging (no guards) ----
        const ushort_t* Ab = (const ushort_t*)A;
        for (int k0 = kbeg; k0 < kend; k0 += 32) {
#pragma unroll
            for (int j = 0; j < 2; j++) {
                int c   = (wave * 2 + j) * 64 + lane;
                int row = c >> 2, kc = c & 3;
                gl2lds16(Ab + (size_t)(m0 + row) * lda + k0 + kc * 8,
                         As + (wave * 2 + j) * 512);
                gl2lds16(Bt + (size_t)row * ldb + k0 + kc * 8,
                         Bs + (wave * 2 + j) * 512);
            }
            __syncthreads();
            mfma_step(As, Bs, acc, wm, wn, quad, l16);
            __syncthreads();
        }
    } else {
        // ---- dual-dtype VGPR staging (guarded rows, zero-fill) ----
        for (int k0 = kbeg; k0 < kend; k0 += 32) {
#pragma unroll
            for (int i = 0; i < 2; i++) {
                int c = t + i * 256;              // 512 chunks of 8 elements
                int row = c >> 2, kc = c & 3;
                uint4 av = make_uint4(0, 0, 0, 0);
                int gr = m0 + row;
                if (gr < M) {
                    size_t base = (size_t)gr * lda + k0 + kc * 8;
                    if (f32a) {
                        const float* Af = (const float*)A + base;
                        float4 lo = *(const float4*)Af;
                        float4 hi = *(const float4*)(Af + 4);
                        av.x = (unsigned)f2b(lo.x) | ((unsigned)f2b(lo.y) << 16);
                        av.y = (unsigned)f2b(lo.z) | ((unsigned)f2b(lo.w) << 16);
                        av.z = (unsigned)f2b(hi.x) | ((unsigned)f2b(hi.y) << 16);
                        av.w = (unsigned)f2b(hi.z) | ((unsigned)f2b(hi.w) << 16);
                    } else {
                        av = *(const uint4*)((const ushort_t*)A + base);
                    }
                }
                *(uint4*)(As + row * 32 + kc * 8) = av;
                uint4 bv = *(const uint4*)(Bt + (size_t)row * ldb + k0 + kc * 8);
                *(uint4*)(Bs + row * 32 + kc * 8) = bv;
            }
            __syncthreads();
            mfma_step(As, Bs, acc, wm, wn, quad, l16);
            __syncthreads();
        }
    }

    // plain stores into this split's private slice (no atomics)
    float* dst = part + (size_t)blockIdx.y * ((size_t)M * 128);
#pragma unroll
    for (int mi = 0; mi < 4; mi++) {
#pragma unroll
        for (int r = 0; r < 4; r++) {
            int row = m0 + wm * 64 + mi * 16 + quad * 4 + r;
            if (row >= M) continue;
#pragma unroll
            for (int ni = 0; ni < 4; ni++) {
                int col = wn * 64 + ni * 16 + l16;
                dst[(size_t)row * 128 + col] = acc[mi][ni][r];
            }
        }
    }
}

// feat cols 64..191 <- sum_s part[s] + b_time; grid NN, 128 threads
__global__ void k_bias_time(const float* __restrict__ part, int nsplit,
                            const ushort_t* __restrict__ bt,
                            ushort_t* __restrict__ feat)
{
    int n = blockIdx.x, o = threadIdx.x;
    float a = b2f(bt[o]);
    for (int s = 0; s < nsplit; ++s)
        a += part[(size_t)s * NN * 128 + (size_t)n * 128 + o];
    feat[(size_t)n * 256 + 64 + o] = f2b(a);
}

// ---------------------------------------------------------------------------
// Build Wcat_t [2304(=9*256), 256] with coalesced reads AND writes via an LDS
// 32x32 tile transpose. Row r*256+o holds column o of W_r over k.
// r<8: W_r = sum_b coeff[r,b]*bases[b];  r==8: self-loop weight.
// grid: 9*64 blocks = (r, kt, ot), 256 threads.
// ---------------------------------------------------------------------------
__global__ void k_build_wcatT(const void* __restrict__ coeff,
                              const void* __restrict__ bases,
                              const void* __restrict__ loopw,
                              ushort_t* __restrict__ Wt, const int* __restrict__ mf)
{
    __shared__ ushort_t tile[32][33];
    int f32m = mf[0];
    int blk = blockIdx.x;
    int r = blk >> 6, kt = (blk >> 3) & 7, ot = blk & 7;
    int k0 = kt * 32, o0 = ot * 32;
    int oi = threadIdx.x & 31, k4 = threadIdx.x >> 5;   // k4 in 0..7
    float cf[8];
    if (r < 8) {
#pragma unroll
        for (int b = 0; b < 8; b++) cf[b] = ldf(coeff, r * 8 + b, f32m);
    }
#pragma unroll
    for (int p = 0; p < 4; ++p) {
        int ki = k4 * 4 + p, k = k0 + ki, o = o0 + oi;
        float acc;
        if (r == 8) {
            acc = ldf(loopw, (size_t)k * 256 + o, f32m);
        } else {
            acc = 0.f;
#pragma unroll
            for (int b = 0; b < 8; b++)
                acc += cf[b] * ldf(bases, ((size_t)b * 256 + k) * 256 + o, f32m);
        }
        tile[ki][oi] = f2b(acc);
    }
    __syncthreads();
    int ki2 = threadIdx.x & 31, o4 = threadIdx.x >> 5;
#pragma unroll
    for (int p = 0; p < 4; ++p) {
        int o2 = o4 * 4 + p;
        Wt[((size_t)(r * 256 + o0 + o2)) * 256 + k0 + ki2] = tile[ki2][o2];
    }
}

// generic coalesced transpose: raw in [rows][cols] -> bf16 out[o][k] (ld=ldout)
// rows, cols multiples of 32; grid (rows/32, cols/32), 256 threads.
__global__ void k_trans32(const void* __restrict__ in, ushort_t* __restrict__ out,
                          int cols, int ldout, const int* __restrict__ mf)
{
    __shared__ ushort_t tile[32][33];
    int f32m = mf[0];
    int k0 = blockIdx.x * 32, o0 = blockIdx.y * 32;
    int oi = threadIdx.x & 31, k4 = threadIdx.x >> 5;
#pragma unroll
    for (int p = 0; p < 4; ++p) {
        int ki = k4 * 4 + p;
        tile[ki][oi] = f2b(ldf(in, (size_t)(k0 + ki) * cols + (o0 + oi), f32m));
    }
    __syncthreads();
    int ki2 = threadIdx.x & 31, o4 = threadIdx.x >> 5;
#pragma unroll
    for (int p = 0; p < 4; ++p) {
        int o2 = o4 * 4 + p;
        out[(size_t)(o0 + o2) * ldout + k0 + ki2] = tile[ki2][o2];
    }
}

// bias_cat[o] = b_fuse[o] + b_fuse_kg[o]; 1 block, 256 threads
__global__ void k_biasfuse(const void* __restrict__ bf, const void* __restrict__ bfk,
                           ushort_t* __restrict__ bias_cat, const int* __restrict__ mf)
{
    int f32m = mf[0];
    int o = threadIdx.x;
    bias_cat[o] = f2b(ldf(bf, o, f32m) + ldf(bfk, o, f32m));
}

// poi (64 cols @0) + road (64 cols @192) projections; grid NN, 128 threads
__global__ void k_inproj(const void* __restrict__ poi, const void* __restrict__ Wp,
                         const void* __restrict__ bp,
                         const void* __restrict__ road, const void* __restrict__ Wr,
                         const void* __restrict__ br,
                         ushort_t* __restrict__ feat, const int* __restrict__ mf)
{
    int f32m = mf[0];
    int n = blockIdx.x, t = threadIdx.x;
    if (t < 64) {
        float a = ldf(bp, t, f32m);
#pragma unroll
        for (int k = 0; k < 12; k++)
            a += ldf(poi, (size_t)n * 12 + k, f32m) * ldf(Wp, k * 64 + t, f32m);
        feat[(size_t)n * 256 + t] = f2b(a);
    } else {
        int o = t - 64;
        float a = ldf(br, o, f32m);
#pragma unroll
        for (int k = 0; k < 32; k++)
            a += ldf(road, (size_t)n * 32 + k, f32m) * ldf(Wr, k * 64 + o, f32m);
        feat[(size_t)n * 256 + 192 + o] = f2b(a);
    }
}

// ------------------------- CSR build (per graph) ---------------------------
__global__ void k_zero(int* __restrict__ p, int n)
{
    int i = blockIdx.x * 256 + threadIdx.x;
    if (i < n) p[i] = 0;
}
__global__ void k_count(const int* __restrict__ dst, int* __restrict__ deg, int e)
{
    int i = blockIdx.x * 256 + threadIdx.x;
    if (i < e) atomicAdd(&deg[dst[i]], 1);
}
__global__ void k_scan1(const int* __restrict__ deg, int* __restrict__ partial,
                        int* __restrict__ bsum, int n)
{
    int t = threadIdx.x, b = blockIdx.x;
    int i = b * 256 + t;
    int v = (i < n) ? deg[i] : 0;
    int lane = t & 63, w = t >> 6;
    int x = v;
#pragma unroll
    for (int d = 1; d < 64; d <<= 1) {
        int y = __shfl_up(x, d);
        if (lane >= d) x += y;
    }
    __shared__ int wt[4];
    if (lane == 63) wt[w] = x;
    __syncthreads();
    int woff = 0;
    for (int j = 0; j < 4; j++) if (j < w) woff += wt[j];
    int incl = x + woff;
    if (i < n) partial[i] = incl - v;     // block-local exclusive scan
    if (t == 255) bsum[b] = incl;
}
__global__ void k_scan2(const int* __restrict__ bsum, int* __restrict__ boff, int nb)
{
    int t = threadIdx.x;
    int v = (t < nb) ? bsum[t] : 0;
    int lane = t & 63, w = t >> 6;
    int x = v;
#pragma unroll
    for (int d = 1; d < 64; d <<= 1) {
        int y = __shfl_up(x, d);
        if (lane >= d) x += y;
    }
    __shared__ int wt[4];
    if (lane == 63) wt[w] = x;
    __syncthreads();
    int woff = 0;
    for (int j = 0; j < 4; j++) if (j < w) woff += wt[j];
    boff[t] = (x + woff) - v;             // exclusive scan of block sums
}
__global__ void k_scan3(const int* __restrict__ boff, int* __restrict__ rs,
                        int* __restrict__ cur, int n)
{
    int i = blockIdx.x * 256 + threadIdx.x;
    if (i < n) {
        int v = rs[i] + boff[blockIdx.x];
        rs[i] = v;
        cur[i] = v;
    }
}
__global__ void k_fill(const int* __restrict__ src, const int* __restrict__ dst,
                       const int* __restrict__ et, int* __restrict__ cur,
                       int* __restrict__ sorted, int e)
{
    int i = blockIdx.x * 256 + threadIdx.x;
    if (i < e) {
        int pos = atomicAdd(&cur[dst[i]], 1);
        sorted[pos] = (src[i] << 3) | et[i];   // etype in [0,8)
    }
}

// ---------------------------------------------------------------------------
// Full-range aggregation (nch==1 fast path): one wave per dst node, ALL 9
// weight blocks in tb (ldt=2304). No per-edge relation-range branch -> the
// compiler can batch the dependent sorted[]->gather chains; 4x unrolled so
// 4 row-gathers are in flight. Accumulation order is IDENTICAL to k_agg2
// (bias, self-loop, edges in CSR order; per-edge component order) so results
// are bit-identical.
// ---------------------------------------------------------------------------
__global__ __launch_bounds__(256) void k_agg_full(
    const ushort_t* __restrict__ tb,
    const int* __restrict__ rs, const int* __restrict__ deg,
    const int* __restrict__ sorted, const ushort_t* __restrict__ bias,
    ushort_t* __restrict__ out, int ldo, int col0, int act, int n_nodes)
{
    int w = blockIdx.x * 4 + (threadIdx.x >> 6);
    if (w >= n_nodes) return;
    int lane = threadIdx.x & 63;
    int lo = lane * 4;

    float a0 = b2f(bias[lo + 0]);
    float a1 = b2f(bias[lo + 1]);
    float a2 = b2f(bias[lo + 2]);
    float a3 = b2f(bias[lo + 3]);
    {   // self-loop block 8
        ushort4 lv = *(const ushort4*)(tb + (size_t)w * NC + 8 * 256 + lo);
        a0 += b2f(lv.x); a1 += b2f(lv.y); a2 += b2f(lv.z); a3 += b2f(lv.w);
    }
    int s = rs[w], cnt = deg[w];
    int j = 0;
    for (; j + 4 <= cnt; j += 4) {
        int p0 = sorted[s + j + 0];
        int p1 = sorted[s + j + 1];
        int p2 = sorted[s + j + 2];
        int p3 = sorted[s + j + 3];
        ushort4 v0 = *(const ushort4*)(tb + ((size_t)(p0 >> 3) * 9 + (p0 & 7)) * 256 + lo);
        ushort4 v1 = *(const ushort4*)(tb + ((size_t)(p1 >> 3) * 9 + (p1 & 7)) * 256 + lo);
        ushort4 v2 = *(const ushort4*)(tb + ((size_t)(p2 >> 3) * 9 + (p2 & 7)) * 256 + lo);
        ushort4 v3 = *(const ushort4*)(tb + ((size_t)(p3 >> 3) * 9 + (p3 & 7)) * 256 + lo);
        a0 += b2f(v0.x); a1 += b2f(v0.y); a2 += b2f(v0.z); a3 += b2f(v0.w);
        a0 += b2f(v1.x); a1 += b2f(v1.y); a2 += b2f(v1.z); a3 += b2f(v1.w);
        a0 += b2f(v2.x); a1 += b2f(v2.y); a2 += b2f(v2.z); a3 += b2f(v2.w);
        a0 += b2f(v3.x); a1 += b2f(v3.y); a2 += b2f(v3.z); a3 += b2f(v3.w);
    }
    for (; j < cnt; ++j) {
        int p = sorted[s + j];
        ushort4 v = *(const ushort4*)(tb + ((size_t)(p >> 3) * 9 + (p & 7)) * 256 + lo);
        a0 += b2f(v.x); a1 += b2f(v.y); a2 += b2f(v.z); a3 += b2f(v.w);
    }
    if (act) {
        a0 = fmaxf(a0, 0.f); a1 = fmaxf(a1, 0.f);
        a2 = fmaxf(a2, 0.f); a3 = fmaxf(a3, 0.f);
    }
    ushort4 o;
    o.x = f2b(a0); o.y = f2b(a1); o.z = f2b(a2); o.w = f2b(a3);
    *(ushort4*)(out + (size_t)w * ldo + col0 + lo) = o;
}

// ---------------------------------------------------------------------------
// Chunked aggregation fallback (ws too small for full tbuf): unchanged.
// ---------------------------------------------------------------------------
__global__ __launch_bounds__(256) void k_agg2(
    const ushort_t* __restrict__ tb, int ldt,
    const int* __restrict__ rs, const int* __restrict__ deg,
    const int* __restrict__ sorted, const ushort_t* __restrict__ bias,
    float* __restrict__ accf, ushort_t* __restrict__ out,
    int ldo, int col0, int act, int b0, int b1, int flags, int n_nodes)
{
    int w = blockIdx.x * 4 + (threadIdx.x >> 6);
    if (w >= n_nodes) return;
    int lane = threadIdx.x & 63;

    float a0, a1, a2, a3;
    if (flags & 1) {
        a0 = b2f(bias[lane * 4 + 0]);
        a1 = b2f(bias[lane * 4 + 1]);
        a2 = b2f(bias[lane * 4 + 2]);
        a3 = b2f(bias[lane * 4 + 3]);
    } else {
        float4 v = *(const float4*)(accf + (size_t)w * 256 + lane * 4);
        a0 = v.x; a1 = v.y; a2 = v.z; a3 = v.w;
    }
    if (b0 <= 8 && 8 < b1) {                 // self-loop block in this chunk
        ushort4 lv = *(const ushort4*)(tb + (size_t)w * ldt + (8 - b0) * 256 + lane * 4);
        a0 += b2f(lv.x); a1 += b2f(lv.y); a2 += b2f(lv.z); a3 += b2f(lv.w);
    }
    int s = rs[w], cnt = deg[w];
    for (int j = 0; j < cnt; ++j) {
        int p = sorted[s + j];
        int r = p & 7;
        if (r >= b0 && r < b1) {
            const ushort_t* q = tb + (size_t)(p >> 3) * ldt + (r - b0) * 256 + lane * 4;
            ushort4 v = *(const ushort4*)q;
            a0 += b2f(v.x); a1 += b2f(v.y); a2 += b2f(v.z); a3 += b2f(v.w);
        }
    }
    if (flags & 2) {
        if (act) {
            a0 = fmaxf(a0, 0.f); a1 = fmaxf(a1, 0.f);
            a2 = fmaxf(a2, 0.f); a3 = fmaxf(a3, 0.f);
        }
        ushort4 o;
        o.x = f2b(a0); o.y = f2b(a1); o.z = f2b(a2); o.w = f2b(a3);
        *(ushort4*)(out + (size_t)w * ldo + col0 + lane * 4) = o;
    } else {
        *(float4*)(accf + (size_t)w * 256 + lane * 4) = make_float4(a0, a1, a2, a3);
    }
}

// ---------------------------------------------------------------------------
extern "C" void kernel_launch(void* const* d_in, const int* in_sizes, int n_in,
                              void* d_out, int out_size, void* d_ws, size_t ws_size,
                              hipStream_t stream)
{
    const void* poi    = d_in[0];
    const void* timeD  = d_in[1];
    const void* roadF  = d_in[2];
    const void* W_poi  = d_in[3];
    const void* b_poi  = d_in[4];
    const void* W_time = d_in[5];
    const void* b_time = d_in[6];
    const void* W_road = d_in[7];
    const void* b_road = d_in[8];
    // relconv param sets: a1=9..12, a2=13..16, n1=17..20, n2=21..24
    const void* W_fuse  = d_in[25];
    const void* b_fuse  = d_in[26];
    const void* W_fusek = d_in[27];
    const void* b_fusek = d_in[28];
    const int* g_src[2] = {(const int*)d_in[29], (const int*)d_in[32]};
    const int* g_dst[2] = {(const int*)d_in[30], (const int*)d_in[33]};
    const int* g_typ[2] = {(const int*)d_in[31], (const int*)d_in[34]};

    char* p = (char*)d_ws;
    auto alloc = [&](size_t bytes) -> char* {
        char* r = p;
        p += (bytes + 255) & ~(size_t)255;
        return r;
    };
    // ---- fixed allocations (~65 MB) ----
    int*      flags   = (int*)alloc(2 * 4);          // [0]=f32mode, [1]=0
    ushort_t* feat    = (ushort_t*)alloc((size_t)NN * 256 * 2);
    ushort_t* h1      = (ushort_t*)alloc((size_t)NN * 256 * 2);
    ushort_t* fused   = (ushort_t*)alloc((size_t)NN * 512 * 2);
    float*    accf    = (float*)alloc((size_t)NN * 256 * 4);  // rgcn chunk accum
    ushort_t* wcat    = (ushort_t*)alloc((size_t)NC * 256 * 2);
    ushort_t* wtt     = (ushort_t*)alloc((size_t)128 * TD * 2);
    ushort_t* wft     = (ushort_t*)alloc((size_t)256 * 512 * 2);
    ushort_t* biascat = (ushort_t*)alloc(256 * 2);
    ushort_t* btws    = (ushort_t*)alloc(128 * 2);   // b_time normalized
    ushort_t* biws    = (ushort_t*)alloc(256 * 2);   // per-layer bias normalized
    int* deg    = (int*)alloc((size_t)NN * 4);
    int* rs     = (int*)alloc((size_t)NN * 4);
    int* cur    = (int*)alloc((size_t)NN * 4);
    int* sorted = (int*)alloc((size_t)EE * 4);
    int* bsum   = (int*)alloc(256 * 4);
    int* boff   = (int*)alloc(256 * 4);

    // ---- adaptive split-K partial slices (no atomics) ----
    size_t psl       = (size_t)NN * 128 * 4;         // one slice: 10.24 MB
    size_t per_block = (size_t)NN * 256 * 2;         // tbuf block: 10.24 MB
    size_t used0 = (size_t)(p - (char*)d_ws);
    int SPLITS;
    float* tpart;
    if (ws_size > used0 + per_block + 512 + psl) {
        size_t s = (ws_size - used0 - per_block - 512) / psl;
        SPLITS = (int)(s > 6 ? 6 : s);
        tpart  = (float*)alloc(psl * SPLITS);
    } else {
        tpart  = accf;                                // accf holds 2 slices
        SPLITS = 2;
    }
    const int KC = TD / SPLITS;                       // all of 1..6 divide 2880

    // ---- adaptive tbuf: C weight-blocks (256 cols each) per GEMM pass ----
    size_t used = (size_t)(p - (char*)d_ws);
    int C = 1;
    if (ws_size > used + 512) {
        size_t c = (ws_size - used - 512) / per_block;
        C = (c < 1) ? 1 : (c > 9 ? 9 : (int)c);
    }
    ushort_t* tbuf = (ushort_t*)alloc(per_block * C);
    const int nch = (9 + C - 1) / C;

    const int SB = (NN + 255) / 256;   // 79 scan blocks
    const int EB = (EE + 255) / 256;   // 1250 edge blocks
    const int MT = (NN + 127) / 128;   // 157 m-tiles

    // --- dtype detect, then weight prep (coalesced LDS-tile transposes) ---
    k_detect<<<1, 256, 0, stream>>>(timeD, flags);
    k_trans32<<<dim3(TD / 32, 128 / 32), 256, 0, stream>>>(W_time, wtt, 128, TD, flags);
    k_trans32<<<dim3(8, 8), 256, 0, stream>>>(W_fuse, wft, 256, 512, flags);
    k_trans32<<<dim3(8, 8), 256, 0, stream>>>(W_fusek, wft + 256, 256, 512, flags);
    k_biasfuse<<<1, 256, 0, stream>>>(b_fuse, b_fusek, biascat, flags);
    k_cvt16<<<1, 256, 0, stream>>>(b_time, btws, 128, flags);

    // --- input feature [NN,256] ---
    k_inproj<<<NN, 128, 0, stream>>>(poi, W_poi, b_poi, roadF, W_road, b_road,
                                     feat, flags);
    // time projection: split-K into private f32 slices, then reduce+bias+cast
    gemm_splitk<<<dim3(MT, SPLITS), 256, 0, stream>>>(timeD, TD, flags, wtt, TD,
                                                      tpart, NN, TD, KC);
    k_bias_time<<<NN, 128, 0, stream>>>(tpart, SPLITS, btws, feat);

    // --- two graphs x two R-GCN layers ---
    for (int g = 0; g < 2; ++g) {
        k_zero<<<SB, 256, 0, stream>>>(deg, NN);
        k_count<<<EB, 256, 0, stream>>>(g_dst[g], deg, EE);
        k_scan1<<<SB, 256, 0, stream>>>(deg, rs, bsum, NN);
        k_scan2<<<1, 256, 0, stream>>>(bsum, boff, SB);
        k_scan3<<<SB, 256, 0, stream>>>(boff, rs, cur, NN);
        k_fill<<<EB, 256, 0, stream>>>(g_src[g], g_dst[g], g_typ[g], cur, sorted, EE);

        for (int l = 0; l < 2; ++l) {
            int rc = g * 2 + l;
            const void* cf  = d_in[9 + rc * 4 + 0];
            const void* bs_ = d_in[9 + rc * 4 + 1];
            const void* lw  = d_in[9 + rc * 4 + 2];
            const void* bi  = d_in[9 + rc * 4 + 3];
            k_build_wcatT<<<9 * 64, 256, 0, stream>>>(cf, bs_, lw, wcat, flags);
            k_cvt16<<<1, 256, 0, stream>>>(bi, biws, 256, flags);
            const ushort_t* Ain = (l == 0) ? feat : h1;
            ushort_t* dest = (l == 0) ? h1 : fused;
            int ldo  = (l == 0) ? 256 : 512;
            int col0 = (l == 0) ? 0 : g * 256;
            int act  = (l == 0) ? 1 : 0;
            if (nch == 1) {
                // full-width projection + branch-free unrolled aggregation
                gemm_bt<<<dim3(MT, 18), 256, 0, stream>>>(
                    Ain, 256, wcat, 256, tbuf, NC, 0, flags + 1, nullptr,
                    NN, NC, 256, 0);
                k_agg_full<<<NN / 4, 256, 0, stream>>>(tbuf, rs, deg, sorted,
                                                       biws, dest, ldo, col0,
                                                       act, NN);
            } else {
                for (int c = 0; c < nch; ++c) {
                    int b0 = c * C;
                    int b1 = (b0 + C < 9) ? b0 + C : 9;
                    int nb = b1 - b0;
                    gemm_bt<<<dim3(MT, nb * 2), 256, 0, stream>>>(
                        Ain, 256, wcat + (size_t)b0 * 256 * 256, 256,
                        tbuf, nb * 256, 0, flags + 1, nullptr, NN, nb * 256, 256, 0);
                    int fl = (c == 0 ? 1 : 0) | (c == nch - 1 ? 2 : 0);
                    k_agg2<<<NN / 4, 256, 0, stream>>>(tbuf, nb * 256, rs, deg, sorted,
                                                       biws, accf, dest, ldo, col0, act,
                                                       b0, b1, fl, NN);
                }
            }
        }
    }

    // --- fusion + exact GELU (output dtype follows input dtype) ---
    gemm_bt<<<dim3(MT, 2), 256, 0, stream>>>(fused, 512, wft, 512,
                                             d_out, 256, 0, flags, biascat,
                                             NN, 256, 512, 2);
}

// Round 7
// 983.840 us; speedup vs baseline: 1.1539x; 1.0258x over previous
//
#include <hip/hip_runtime.h>
#include <math.h>

typedef unsigned short ushort_t;                       // bf16 bit storage
typedef __bf16 bf16x8 __attribute__((ext_vector_type(8)));
typedef float  f32x4  __attribute__((ext_vector_type(4)));

constexpr int NN = 20000;   // nodes
constexpr int EE = 320000;  // edges
constexpr int NC = 2304;    // 9*256 projection width (8 rels + self-loop)
constexpr int TD = 2880;    // time dim

__device__ __forceinline__ float b2f(ushort_t u) {
    return __uint_as_float(((unsigned int)u) << 16);
}
__device__ __forceinline__ ushort_t f2b(float f) {
    unsigned int u = __float_as_uint(f);
    u += 0x7fffu + ((u >> 16) & 1u);                   // round-to-nearest-even
    return (ushort_t)(u >> 16);
}
// dual-dtype load: raw inputs may be f32 or bf16 (runtime-detected flag)
__device__ __forceinline__ float ldf(const void* p, size_t i, int f32m) {
    return f32m ? ((const float*)p)[i] : b2f(((const ushort_t*)p)[i]);
}
// async global->LDS, 16B per lane; LDS dest = wave-uniform base + lane*16
__device__ __forceinline__ void gl2lds16(const ushort_t* g, ushort_t* l) {
    __builtin_amdgcn_global_load_lds(
        (const __attribute__((address_space(1))) void*)g,
        (__attribute__((address_space(3))) void*)l, 16, 0, 0);
}

// shared MFMA inner step: LDS tiles [128 rows x 32 k] -> 4x4 acc of 16x16x32
__device__ __forceinline__ void mfma_step(const ushort_t* As, const ushort_t* Bs,
                                          f32x4 (&acc)[4][4],
                                          int wm, int wn, int quad, int l16)
{
    bf16x8 afr[4], bfr[4];
#pragma unroll
    for (int mi = 0; mi < 4; mi++)
        afr[mi] = *(const bf16x8*)(As + (wm * 64 + mi * 16 + l16) * 32 + quad * 8);
#pragma unroll
    for (int ni = 0; ni < 4; ni++)
        bfr[ni] = *(const bf16x8*)(Bs + (wn * 64 + ni * 16 + l16) * 32 + quad * 8);
#pragma unroll
    for (int mi = 0; mi < 4; mi++)
#pragma unroll
        for (int ni = 0; ni < 4; ni++)
            acc[mi][ni] = __builtin_amdgcn_mfma_f32_16x16x32_bf16(
                afr[mi], bfr[ni], acc[mi][ni], 0, 0, 0);
}

// ---------------------------------------------------------------------------
// Detect input dtype (bf16-stored vs f32-stored). flags[0]=f32mode, flags[1]=0.
// ---------------------------------------------------------------------------
__global__ void k_detect(const void* timeD, int* flags)
{
    __shared__ float mx[256];
    int t = threadIdx.x;
    float m = 0.f;
    for (int i = t; i < 1024; i += 256) {
        float v = fabsf(b2f(((const ushort_t*)timeD)[i]));
        if (!(v < 1e30f)) v = 1e30f;   // NaN/Inf -> huge
        m = fmaxf(m, v);
    }
    mx[t] = m;
    __syncthreads();
    if (t == 0) {
        float mm = 0.f;
        for (int i = 0; i < 256; i++) mm = fmaxf(mm, mx[i]);
        flags[0] = (mm > 1e4f) ? 1 : 0;
        flags[1] = 0;
    }
}

// small dtype-normalizing copy: out (bf16) <- in (f32 or bf16)
__global__ void k_cvt16(const void* __restrict__ in, ushort_t* __restrict__ out,
                        int n, const int* __restrict__ mf)
{
    int f32m = mf[0];
    int i = blockIdx.x * 256 + threadIdx.x;
    if (i < n) out[i] = f32m ? f2b(((const float*)in)[i]) : ((const ushort_t*)in)[i];
}

// ---------------------------------------------------------------------------
// Main bf16 MFMA GEMM (A is a ws bf16 buffer): C = act(A * Bt^T + bias).
// global_load_lds width-16 staging; LDS row stride 32 shorts. Tile 128x128,
// BK=32, 4 waves (2x2). XCD-chunked bijective block remap (m204): blocks with
// flat%8==c land on XCD c; each XCD gets a contiguous m-chunk, n-minor, so
// its A-chunk (~1.3 MB) and the B panel stay L2-resident across n-panels.
// A rows may over-read past M (stays inside d_ws; epilogue masks stores).
// ---------------------------------------------------------------------------
__global__ __launch_bounds__(256) void gemm_bt(
    const ushort_t* __restrict__ A, int lda,
    const ushort_t* __restrict__ Bt, int ldb,
    void* __restrict__ C, int ldc, int col0, const int* __restrict__ of,
    const ushort_t* __restrict__ bias,
    int M, int Ncols, int K, int act)
{
    __shared__ ushort_t As[128 * 32];
    __shared__ ushort_t Bs[128 * 32];

    const int f32o = of[0];
    const int t    = threadIdx.x;
    const int wave = t >> 6, lane = t & 63;
    const int wm   = wave >> 1, wn = wave & 1;
    const int quad = lane >> 4, l16 = lane & 15;

    // bijective XCD-chunk swizzle (m204), n-minor decode
    const int NBx = gridDim.x, NBy = gridDim.y;
    const int total = NBx * NBy;
    const int flat  = blockIdx.y * NBx + blockIdx.x;
    const int xcd = flat & 7, i8 = flat >> 3;
    const int q = total >> 3, r = total & 7;
    const int pos = (xcd < r) ? xcd * (q + 1) + i8
                              : r * (q + 1) + (xcd - r) * q + i8;
    const int m0 = (pos / NBy) * 128, n0 = (pos % NBy) * 128;

    f32x4 acc[4][4];
#pragma unroll
    for (int i = 0; i < 4; i++)
#pragma unroll
        for (int j = 0; j < 4; j++) acc[i][j] = (f32x4){0.f, 0.f, 0.f, 0.f};

    for (int k0 = 0; k0 < K; k0 += 32) {
#pragma unroll
        for (int j = 0; j < 2; j++) {
            int c   = (wave * 2 + j) * 64 + lane;     // 16B chunk id, 512 total
            int row = c >> 2, kc = c & 3;
            ushort_t* ldsbase_a = As + (wave * 2 + j) * 512;  // wave-uniform
            ushort_t* ldsbase_b = Bs + (wave * 2 + j) * 512;
            gl2lds16(A  + (size_t)(m0 + row) * lda + k0 + kc * 8, ldsbase_a);
            gl2lds16(Bt + (size_t)(n0 + row) * ldb + k0 + kc * 8, ldsbase_b);
        }
        __syncthreads();
        mfma_step(As, Bs, acc, wm, wn, quad, l16);
        __syncthreads();
    }

#pragma unroll
    for (int mi = 0; mi < 4; mi++) {
#pragma unroll
        for (int r2 = 0; r2 < 4; r2++) {
            int row = m0 + wm * 64 + mi * 16 + quad * 4 + r2;
            if (row >= M) continue;
#pragma unroll
            for (int ni = 0; ni < 4; ni++) {
                int col = n0 + wn * 64 + ni * 16 + l16;
                float v = acc[mi][ni][r2];
                if (bias) v += b2f(bias[col]);
                if (act == 1) v = fmaxf(v, 0.f);
                else if (act == 2) v = 0.5f * v * (1.f + erff(v * 0.70710678118654752f));
                size_t idx = (size_t)row * ldc + col0 + col;
                if (f32o) ((float*)C)[idx] = v;
                else      ((ushort_t*)C)[idx] = f2b(v);
            }
        }
    }
}

// ---------------------------------------------------------------------------
// Split-K GEMM for the time projection (A raw f32 or bf16, N=128 fixed).
// grid (m_tiles, nsplit); each split writes its PRIVATE f32 partial slice
// part[split][M][128] with plain coalesced stores (no atomics).
// ---------------------------------------------------------------------------
__global__ __launch_bounds__(256) void gemm_splitk(
    const void* __restrict__ A, int lda, const int* __restrict__ af,
    const ushort_t* __restrict__ Bt, int ldb,
    float* __restrict__ part, int M, int K, int KC)
{
    __shared__ ushort_t As[128 * 32];
    __shared__ ushort_t Bs[128 * 32];

    const int f32a = af[0];
    const int t    = threadIdx.x;
    const int wave = t >> 6, lane = t & 63;
    const int wm   = wave >> 1, wn = wave & 1;
    const int quad = lane >> 4, l16 = lane & 15;
    const int m0   = blockIdx.x * 128;
    const int kbeg = blockIdx.y * KC;
    const int kend = (kbeg + KC < K) ? kbeg + KC : K;

    f32x4 acc[4][4];
#pragma unroll
    for (int i = 0; i < 4; i++)
#pragma unroll
        for (int j = 0; j < 4; j++) acc[i][j] = (f32x4){0.f, 0.f, 0.f, 0.f};

    if (!f32a && (m0 + 128 <= M)) {
        // ---- bf16 full-tile fast path: async DMA staging (no guards) ----
        const ushort_t* Ab = (const ushort_t*)A;
        for (int k0 = kbeg; k0 < kend; k0 += 32) {
#pragma unroll
            for (int j = 0; j < 2; j++) {
                int c   = (wave * 2 + j) * 64 + lane;
                int row = c >> 2, kc = c & 3;
                gl2lds16(Ab + (size_t)(m0 + row) * lda + k0 + kc * 8,
                         As + (wave * 2 + j) * 512);
                gl2lds16(Bt + (size_t)row * ldb + k0 + kc * 8,
                         Bs + (wave * 2 + j) * 512);
            }
            __syncthreads();
            mfma_step(As, Bs, acc, wm, wn, quad, l16);
            __syncthreads();
        }
    } else {
        // ---- dual-dtype VGPR staging (guarded rows, zero-fill) ----
        for (int k0 = kbeg; k0 < kend; k0 += 32) {
#pragma unroll
            for (int i = 0; i < 2; i++) {
                int c = t + i * 256;              // 512 chunks of 8 elements
                int row = c >> 2, kc = c & 3;
                uint4 av = make_uint4(0, 0, 0, 0);
                int gr = m0 + row;
                if (gr < M) {
                    size_t base = (size_t)gr * lda + k0 + kc * 8;
                    if (f32a) {
                        const float* Af = (const float*)A + base;
                        float4 lo = *(const float4*)Af;
                        float4 hi = *(const float4*)(Af + 4);
                        av.x = (unsigned)f2b(lo.x) | ((unsigned)f2b(lo.y) << 16);
                        av.y = (unsigned)f2b(lo.z) | ((unsigned)f2b(lo.w) << 16);
                        av.z = (unsigned)f2b(hi.x) | ((unsigned)f2b(hi.y) << 16);
                        av.w = (unsigned)f2b(hi.z) | ((unsigned)f2b(hi.w) << 16);
                    } else {
                        av = *(const uint4*)((const ushort_t*)A + base);
                    }
                }
                *(uint4*)(As + row * 32 + kc * 8) = av;
                uint4 bv = *(const uint4*)(Bt + (size_t)row * ldb + k0 + kc * 8);
                *(uint4*)(Bs + row * 32 + kc * 8) = bv;
            }
            __syncthreads();
            mfma_step(As, Bs, acc, wm, wn, quad, l16);
            __syncthreads();
        }
    }

    // plain stores into this split's private slice (no atomics)
    float* dst = part + (size_t)blockIdx.y * ((size_t)M * 128);
#pragma unroll
    for (int mi = 0; mi < 4; mi++) {
#pragma unroll
        for (int r = 0; r < 4; r++) {
            int row = m0 + wm * 64 + mi * 16 + quad * 4 + r;
            if (row >= M) continue;
#pragma unroll
            for (int ni = 0; ni < 4; ni++) {
                int col = wn * 64 + ni * 16 + l16;
                dst[(size_t)row * 128 + col] = acc[mi][ni][r];
            }
        }
    }
}

// feat cols 64..191 <- sum_s part[s] + b_time; grid NN, 128 threads
__global__ void k_bias_time(const float* __restrict__ part, int nsplit,
                            const ushort_t* __restrict__ bt,
                            ushort_t* __restrict__ feat)
{
    int n = blockIdx.x, o = threadIdx.x;
    float a = b2f(bt[o]);
    for (int s = 0; s < nsplit; ++s)
        a += part[(size_t)s * NN * 128 + (size_t)n * 128 + o];
    feat[(size_t)n * 256 + 64 + o] = f2b(a);
}

// ---------------------------------------------------------------------------
// Build Wcat_t [2304, 256] (one R-GCN layer's 9 stacked W_r^T) with coalesced
// reads AND writes via an LDS 32x32 tile transpose.
// grid: 9*64 blocks = (r, kt, ot), 256 threads.
// ---------------------------------------------------------------------------
__global__ void k_build_wcatT(const void* __restrict__ coeff,
                              const void* __restrict__ bases,
                              const void* __restrict__ loopw,
                              ushort_t* __restrict__ Wt, const int* __restrict__ mf)
{
    __shared__ ushort_t tile[32][33];
    int f32m = mf[0];
    int blk = blockIdx.x;
    int r = blk >> 6, kt = (blk >> 3) & 7, ot = blk & 7;
    int k0 = kt * 32, o0 = ot * 32;
    int oi = threadIdx.x & 31, k4 = threadIdx.x >> 5;   // k4 in 0..7
    float cf[8];
    if (r < 8) {
#pragma unroll
        for (int b = 0; b < 8; b++) cf[b] = ldf(coeff, r * 8 + b, f32m);
    }
#pragma unroll
    for (int p = 0; p < 4; ++p) {
        int ki = k4 * 4 + p, k = k0 + ki, o = o0 + oi;
        float acc;
        if (r == 8) {
            acc = ldf(loopw, (size_t)k * 256 + o, f32m);
        } else {
            acc = 0.f;
#pragma unroll
            for (int b = 0; b < 8; b++)
                acc += cf[b] * ldf(bases, ((size_t)b * 256 + k) * 256 + o, f32m);
        }
        tile[ki][oi] = f2b(acc);
    }
    __syncthreads();
    int ki2 = threadIdx.x & 31, o4 = threadIdx.x >> 5;
#pragma unroll
    for (int p = 0; p < 4; ++p) {
        int o2 = o4 * 4 + p;
        Wt[((size_t)(r * 256 + o0 + o2)) * 256 + k0 + ki2] = tile[ki2][o2];
    }
}

// generic coalesced transpose: raw in [rows][cols] -> bf16 out[o][k] (ld=ldout)
__global__ void k_trans32(const void* __restrict__ in, ushort_t* __restrict__ out,
                          int cols, int ldout, const int* __restrict__ mf)
{
    __shared__ ushort_t tile[32][33];
    int f32m = mf[0];
    int k0 = blockIdx.x * 32, o0 = blockIdx.y * 32;
    int oi = threadIdx.x & 31, k4 = threadIdx.x >> 5;
#pragma unroll
    for (int p = 0; p < 4; ++p) {
        int ki = k4 * 4 + p;
        tile[ki][oi] = f2b(ldf(in, (size_t)(k0 + ki) * cols + (o0 + oi), f32m));
    }
    __syncthreads();
    int ki2 = threadIdx.x & 31, o4 = threadIdx.x >> 5;
#pragma unroll
    for (int p = 0; p < 4; ++p) {
        int o2 = o4 * 4 + p;
        out[(size_t)(o0 + o2) * ldout + k0 + ki2] = tile[ki2][o2];
    }
}

// bias_cat[o] = b_fuse[o] + b_fuse_kg[o]; 1 block, 256 threads
__global__ void k_biasfuse(const void* __restrict__ bf, const void* __restrict__ bfk,
                           ushort_t* __restrict__ bias_cat, const int* __restrict__ mf)
{
    int f32m = mf[0];
    int o = threadIdx.x;
    bias_cat[o] = f2b(ldf(bf, o, f32m) + ldf(bfk, o, f32m));
}

// poi (64 cols @0) + road (64 cols @192) projections; grid NN, 128 threads
__global__ void k_inproj(const void* __restrict__ poi, const void* __restrict__ Wp,
                         const void* __restrict__ bp,
                         const void* __restrict__ road, const void* __restrict__ Wr,
                         const void* __restrict__ br,
                         ushort_t* __restrict__ feat, const int* __restrict__ mf)
{
    int f32m = mf[0];
    int n = blockIdx.x, t = threadIdx.x;
    if (t < 64) {
        float a = ldf(bp, t, f32m);
#pragma unroll
        for (int k = 0; k < 12; k++)
            a += ldf(poi, (size_t)n * 12 + k, f32m) * ldf(Wp, k * 64 + t, f32m);
        feat[(size_t)n * 256 + t] = f2b(a);
    } else {
        int o = t - 64;
        float a = ldf(br, o, f32m);
#pragma unroll
        for (int k = 0; k < 32; k++)
            a += ldf(road, (size_t)n * 32 + k, f32m) * ldf(Wr, k * 64 + o, f32m);
        feat[(size_t)n * 256 + 192 + o] = f2b(a);
    }
}

// ------------------------- CSR build (per graph) ---------------------------
__global__ void k_zero(int* __restrict__ p, int n)
{
    int i = blockIdx.x * 256 + threadIdx.x;
    if (i < n) p[i] = 0;
}
__global__ void k_count(const int* __restrict__ dst, int* __restrict__ deg, int e)
{
    int i = blockIdx.x * 256 + threadIdx.x;
    if (i < e) atomicAdd(&deg[dst[i]], 1);
}
__global__ void k_scan1(const int* __restrict__ deg, int* __restrict__ partial,
                        int* __restrict__ bsum, int n)
{
    int t = threadIdx.x, b = blockIdx.x;
    int i = b * 256 + t;
    int v = (i < n) ? deg[i] : 0;
    int lane = t & 63, w = t >> 6;
    int x = v;
#pragma unroll
    for (int d = 1; d < 64; d <<= 1) {
        int y = __shfl_up(x, d);
        if (lane >= d) x += y;
    }
    __shared__ int wt[4];
    if (lane == 63) wt[w] = x;
    __syncthreads();
    int woff = 0;
    for (int j = 0; j < 4; j++) if (j < w) woff += wt[j];
    int incl = x + woff;
    if (i < n) partial[i] = incl - v;     // block-local exclusive scan
    if (t == 255) bsum[b] = incl;
}
__global__ void k_scan2(const int* __restrict__ bsum, int* __restrict__ boff, int nb)
{
    int t = threadIdx.x;
    int v = (t < nb) ? bsum[t] : 0;
    int lane = t & 63, w = t >> 6;
    int x = v;
#pragma unroll
    for (int d = 1; d < 64; d <<= 1) {
        int y = __shfl_up(x, d);
        if (lane >= d) x += y;
    }
    __shared__ int wt[4];
    if (lane == 63) wt[w] = x;
    __syncthreads();
    int woff = 0;
    for (int j = 0; j < 4; j++) if (j < w) woff += wt[j];
    boff[t] = (x + woff) - v;             // exclusive scan of block sums
}
__global__ void k_scan3(const int* __restrict__ boff, int* __restrict__ rs,
                        int* __restrict__ cur, int n)
{
    int i = blockIdx.x * 256 + threadIdx.x;
    if (i < n) {
        int v = rs[i] + boff[blockIdx.x];
        rs[i] = v;
        cur[i] = v;
    }
}
__global__ void k_fill(const int* __restrict__ src, const int* __restrict__ dst,
                       const int* __restrict__ et, int* __restrict__ cur,
                       int* __restrict__ sorted, int e)
{
    int i = blockIdx.x * 256 + threadIdx.x;
    if (i < e) {
        int pos = atomicAdd(&cur[dst[i]], 1);
        sorted[pos] = (src[i] << 3) | et[i];   // etype in [0,8)
    }
}

// ---------------------------------------------------------------------------
// Full-range aggregation: one wave per dst node; projections for this layer
// live at tb[row*ldt + colbase + rel*256 ..], self-loop at rel=8. Branch-free
// 4x-unrolled gather chain; accumulation order identical to the chunked path.
// ---------------------------------------------------------------------------
__global__ __launch_bounds__(256) void k_agg_full(
    const ushort_t* __restrict__ tb, int ldt, int colbase,
    const int* __restrict__ rs, const int* __restrict__ deg,
    const int* __restrict__ sorted, const ushort_t* __restrict__ bias,
    ushort_t* __restrict__ out, int ldo, int col0, int act, int n_nodes)
{
    int w = blockIdx.x * 4 + (threadIdx.x >> 6);
    if (w >= n_nodes) return;
    int lane = threadIdx.x & 63;
    int lo = lane * 4;
    const ushort_t* tbb = tb + colbase + lo;

    float a0 = b2f(bias[lo + 0]);
    float a1 = b2f(bias[lo + 1]);
    float a2 = b2f(bias[lo + 2]);
    float a3 = b2f(bias[lo + 3]);
    {   // self-loop block 8
        ushort4 lv = *(const ushort4*)(tbb + (size_t)w * ldt + 2048);
        a0 += b2f(lv.x); a1 += b2f(lv.y); a2 += b2f(lv.z); a3 += b2f(lv.w);
    }
    int s = rs[w], cnt = deg[w];
    int j = 0;
    for (; j + 4 <= cnt; j += 4) {
        int p0 = sorted[s + j + 0];
        int p1 = sorted[s + j + 1];
        int p2 = sorted[s + j + 2];
        int p3 = sorted[s + j + 3];
        ushort4 v0 = *(const ushort4*)(tbb + (size_t)(p0 >> 3) * ldt + (p0 & 7) * 256);
        ushort4 v1 = *(const ushort4*)(tbb + (size_t)(p1 >> 3) * ldt + (p1 & 7) * 256);
        ushort4 v2 = *(const ushort4*)(tbb + (size_t)(p2 >> 3) * ldt + (p2 & 7) * 256);
        ushort4 v3 = *(const ushort4*)(tbb + (size_t)(p3 >> 3) * ldt + (p3 & 7) * 256);
        a0 += b2f(v0.x); a1 += b2f(v0.y); a2 += b2f(v0.z); a3 += b2f(v0.w);
        a0 += b2f(v1.x); a1 += b2f(v1.y); a2 += b2f(v1.z); a3 += b2f(v1.w);
        a0 += b2f(v2.x); a1 += b2f(v2.y); a2 += b2f(v2.z); a3 += b2f(v2.w);
        a0 += b2f(v3.x); a1 += b2f(v3.y); a2 += b2f(v3.z); a3 += b2f(v3.w);
    }
    for (; j < cnt; ++j) {
        int p = sorted[s + j];
        ushort4 v = *(const ushort4*)(tbb + (size_t)(p >> 3) * ldt + (p & 7) * 256);
        a0 += b2f(v.x); a1 += b2f(v.y); a2 += b2f(v.z); a3 += b2f(v.w);
    }
    if (act) {
        a0 = fmaxf(a0, 0.f); a1 = fmaxf(a1, 0.f);
        a2 = fmaxf(a2, 0.f); a3 = fmaxf(a3, 0.f);
    }
    ushort4 o;
    o.x = f2b(a0); o.y = f2b(a1); o.z = f2b(a2); o.w = f2b(a3);
    *(ushort4*)(out + (size_t)w * ldo + col0 + lo) = o;
}

// ---------------------------------------------------------------------------
// Chunked aggregation fallback (ws too small for full tbuf): unchanged.
// ---------------------------------------------------------------------------
__global__ __launch_bounds__(256) void k_agg2(
    const ushort_t* __restrict__ tb, int ldt,
    const int* __restrict__ rs, const int* __restrict__ deg,
    const int* __restrict__ sorted, const ushort_t* __restrict__ bias,
    float* __restrict__ accf, ushort_t* __restrict__ out,
    int ldo, int col0, int act, int b0, int b1, int flags, int n_nodes)
{
    int w = blockIdx.x * 4 + (threadIdx.x >> 6);
    if (w >= n_nodes) return;
    int lane = threadIdx.x & 63;

    float a0, a1, a2, a3;
    if (flags & 1) {
        a0 = b2f(bias[lane * 4 + 0]);
        a1 = b2f(bias[lane * 4 + 1]);
        a2 = b2f(bias[lane * 4 + 2]);
        a3 = b2f(bias[lane * 4 + 3]);
    } else {
        float4 v = *(const float4*)(accf + (size_t)w * 256 + lane * 4);
        a0 = v.x; a1 = v.y; a2 = v.z; a3 = v.w;
    }
    if (b0 <= 8 && 8 < b1) {                 // self-loop block in this chunk
        ushort4 lv = *(const ushort4*)(tb + (size_t)w * ldt + (8 - b0) * 256 + lane * 4);
        a0 += b2f(lv.x); a1 += b2f(lv.y); a2 += b2f(lv.z); a3 += b2f(lv.w);
    }
    int s = rs[w], cnt = deg[w];
    for (int j = 0; j < cnt; ++j) {
        int p = sorted[s + j];
        int r = p & 7;
        if (r >= b0 && r < b1) {
            const ushort_t* q = tb + (size_t)(p >> 3) * ldt + (r - b0) * 256 + lane * 4;
            ushort4 v = *(const ushort4*)q;
            a0 += b2f(v.x); a1 += b2f(v.y); a2 += b2f(v.z); a3 += b2f(v.w);
        }
    }
    if (flags & 2) {
        if (act) {
            a0 = fmaxf(a0, 0.f); a1 = fmaxf(a1, 0.f);
            a2 = fmaxf(a2, 0.f); a3 = fmaxf(a3, 0.f);
        }
        ushort4 o;
        o.x = f2b(a0); o.y = f2b(a1); o.z = f2b(a2); o.w = f2b(a3);
        *(ushort4*)(out + (size_t)w * ldo + col0 + lane * 4) = o;
    } else {
        *(float4*)(accf + (size_t)w * 256 + lane * 4) = make_float4(a0, a1, a2, a3);
    }
}

// ---------------------------------------------------------------------------
extern "C" void kernel_launch(void* const* d_in, const int* in_sizes, int n_in,
                              void* d_out, int out_size, void* d_ws, size_t ws_size,
                              hipStream_t stream)
{
    const void* poi    = d_in[0];
    const void* timeD  = d_in[1];
    const void* roadF  = d_in[2];
    const void* W_poi  = d_in[3];
    const void* b_poi  = d_in[4];
    const void* W_time = d_in[5];
    const void* b_time = d_in[6];
    const void* W_road = d_in[7];
    const void* b_road = d_in[8];
    // relconv param sets: a1=9..12, a2=13..16, n1=17..20, n2=21..24
    const void* W_fuse  = d_in[25];
    const void* b_fuse  = d_in[26];
    const void* W_fusek = d_in[27];
    const void* b_fusek = d_in[28];
    const int* g_src[2] = {(const int*)d_in[29], (const int*)d_in[32]};
    const int* g_dst[2] = {(const int*)d_in[30], (const int*)d_in[33]};
    const int* g_typ[2] = {(const int*)d_in[31], (const int*)d_in[34]};

    char* p = (char*)d_ws;
    auto alloc = [&](size_t bytes) -> char* {
        char* r = p;
        p += (bytes + 255) & ~(size_t)255;
        return r;
    };
    // ---- fixed allocations ----
    int*      flags   = (int*)alloc(2 * 4);          // [0]=f32mode, [1]=0
    ushort_t* feat    = (ushort_t*)alloc((size_t)NN * 256 * 2);
    ushort_t* h1a     = (ushort_t*)alloc((size_t)NN * 256 * 2);
    ushort_t* h1b     = (ushort_t*)alloc((size_t)NN * 256 * 2);
    ushort_t* fused   = (ushort_t*)alloc((size_t)NN * 512 * 2);
    float*    accf    = (float*)alloc((size_t)NN * 256 * 4);  // fallback accum
    ushort_t* wcat    = (ushort_t*)alloc((size_t)2 * NC * 256 * 2);  // 2 sets
    ushort_t* wtt     = (ushort_t*)alloc((size_t)128 * TD * 2);
    ushort_t* wft     = (ushort_t*)alloc((size_t)256 * 512 * 2);
    ushort_t* biascat = (ushort_t*)alloc(256 * 2);
    ushort_t* btws    = (ushort_t*)alloc(128 * 2);   // b_time normalized
    ushort_t* biws0   = (ushort_t*)alloc(256 * 2);   // per-layer bias (set 0)
    ushort_t* biws1   = (ushort_t*)alloc(256 * 2);   // per-layer bias (set 1)
    int* deg[2]; int* rs[2]; int* sorted[2];
    deg[0] = (int*)alloc((size_t)NN * 4);  deg[1] = (int*)alloc((size_t)NN * 4);
    rs[0]  = (int*)alloc((size_t)NN * 4);  rs[1]  = (int*)alloc((size_t)NN * 4);
    sorted[0] = (int*)alloc((size_t)EE * 4);
    sorted[1] = (int*)alloc((size_t)EE * 4);
    int* cur  = (int*)alloc((size_t)NN * 4);
    int* bsum = (int*)alloc(256 * 4);
    int* boff = (int*)alloc(256 * 4);

    // ---- adaptive split-K partial slices (no atomics) ----
    size_t psl       = (size_t)NN * 128 * 4;         // one slice: 10.24 MB
    size_t per_tb    = (size_t)NN * NC * 2;          // full tbuf: 92.16 MB
    size_t per_block = (size_t)NN * 256 * 2;         // chunk block: 10.24 MB
    size_t used0 = (size_t)(p - (char*)d_ws);
    int SPLITS;
    float* tpart;
    if (ws_size > used0 + per_block + 512 + psl) {
        size_t s = (ws_size - used0 - per_block - 512) / psl;
        SPLITS = (int)(s > 6 ? 6 : s);
        tpart  = (float*)alloc(psl * SPLITS);
    } else {
        tpart  = accf;                                // accf holds 2 slices
        SPLITS = 2;
    }
    const int KC = TD / SPLITS;                       // all of 1..6 divide 2880

    // ---- tbuf: merged (2 full layer-1 panels) | full | chunked fallback ----
    size_t used = (size_t)(p - (char*)d_ws);
    int MERGED = 0, C = 1;
    ushort_t* tbuf;
    if (ws_size > used + 2 * per_tb + 512) {
        MERGED = 1;
        tbuf = (ushort_t*)alloc(2 * per_tb);
    } else {
        if (ws_size > used + 512) {
            size_t c = (ws_size - used - 512) / per_block;
            C = (c < 1) ? 1 : (c > 9 ? 9 : (int)c);
        }
        tbuf = (ushort_t*)alloc(per_block * C);
    }
    const int nch = (9 + C - 1) / C;

    const int SB = (NN + 255) / 256;   // 79 scan blocks
    const int EB = (EE + 255) / 256;   // 1250 edge blocks
    const int MT = (NN + 127) / 128;   // 157 m-tiles

    // --- dtype detect, then weight prep (coalesced LDS-tile transposes) ---
    k_detect<<<1, 256, 0, stream>>>(timeD, flags);
    k_trans32<<<dim3(TD / 32, 128 / 32), 256, 0, stream>>>(W_time, wtt, 128, TD, flags);
    k_trans32<<<dim3(8, 8), 256, 0, stream>>>(W_fuse, wft, 256, 512, flags);
    k_trans32<<<dim3(8, 8), 256, 0, stream>>>(W_fusek, wft + 256, 256, 512, flags);
    k_biasfuse<<<1, 256, 0, stream>>>(b_fuse, b_fusek, biascat, flags);
    k_cvt16<<<1, 256, 0, stream>>>(b_time, btws, 128, flags);

    // --- input feature [NN,256] ---
    k_inproj<<<NN, 128, 0, stream>>>(poi, W_poi, b_poi, roadF, W_road, b_road,
                                     feat, flags);
    gemm_splitk<<<dim3(MT, SPLITS), 256, 0, stream>>>(timeD, TD, flags, wtt, TD,
                                                      tpart, NN, TD, KC);
    k_bias_time<<<NN, 128, 0, stream>>>(tpart, SPLITS, btws, feat);

    // --- CSR build for both graphs (double-buffered) ---
    for (int g = 0; g < 2; ++g) {
        k_zero<<<SB, 256, 0, stream>>>(deg[g], NN);
        k_count<<<EB, 256, 0, stream>>>(g_dst[g], deg[g], EE);
        k_scan1<<<SB, 256, 0, stream>>>(deg[g], rs[g], bsum, NN);
        k_scan2<<<1, 256, 0, stream>>>(bsum, boff, SB);
        k_scan3<<<SB, 256, 0, stream>>>(boff, rs[g], cur, NN);
        k_fill<<<EB, 256, 0, stream>>>(g_src[g], g_dst[g], g_typ[g], cur,
                                       sorted[g], EE);
    }

    if (MERGED) {
        // --- layer 1 (both graphs) as ONE wide GEMM [NN, 4608] ---
        k_build_wcatT<<<9 * 64, 256, 0, stream>>>(d_in[9], d_in[10], d_in[11],
                                                  wcat, flags);
        k_build_wcatT<<<9 * 64, 256, 0, stream>>>(d_in[17], d_in[18], d_in[19],
                                                  wcat + (size_t)NC * 256, flags);
        k_cvt16<<<1, 256, 0, stream>>>(d_in[12], biws0, 256, flags);
        k_cvt16<<<1, 256, 0, stream>>>(d_in[20], biws1, 256, flags);
        gemm_bt<<<dim3(MT, 36), 256, 0, stream>>>(
            feat, 256, wcat, 256, tbuf, 2 * NC, 0, flags + 1, nullptr,
            NN, 2 * NC, 256, 0);
        k_agg_full<<<NN / 4, 256, 0, stream>>>(tbuf, 2 * NC, 0, rs[0], deg[0],
                                               sorted[0], biws0, h1a, 256, 0, 1, NN);
        k_agg_full<<<NN / 4, 256, 0, stream>>>(tbuf, 2 * NC, NC, rs[1], deg[1],
                                               sorted[1], biws1, h1b, 256, 0, 1, NN);
        // --- layer 2 per graph ---
        for (int g = 0; g < 2; ++g) {
            int base = (g == 0) ? 13 : 21;   // a2 / n2 param sets
            k_build_wcatT<<<9 * 64, 256, 0, stream>>>(d_in[base], d_in[base + 1],
                                                      d_in[base + 2], wcat, flags);
            k_cvt16<<<1, 256, 0, stream>>>(d_in[base + 3], biws0, 256, flags);
            const ushort_t* Ain = (g == 0) ? h1a : h1b;
            gemm_bt<<<dim3(MT, 18), 256, 0, stream>>>(
                Ain, 256, wcat, 256, tbuf, NC, 0, flags + 1, nullptr,
                NN, NC, 256, 0);
            k_agg_full<<<NN / 4, 256, 0, stream>>>(tbuf, NC, 0, rs[g], deg[g],
                                                   sorted[g], biws0, fused, 512,
                                                   g * 256, 0, NN);
        }
    } else {
        // --- fallback: per-graph per-layer (chunked if needed) ---
        for (int g = 0; g < 2; ++g) {
            for (int l = 0; l < 2; ++l) {
                int rc = g * 2 + l;
                const void* cf  = d_in[9 + rc * 4 + 0];
                const void* bs_ = d_in[9 + rc * 4 + 1];
                const void* lw  = d_in[9 + rc * 4 + 2];
                const void* bi  = d_in[9 + rc * 4 + 3];
                k_build_wcatT<<<9 * 64, 256, 0, stream>>>(cf, bs_, lw, wcat, flags);
                k_cvt16<<<1, 256, 0, stream>>>(bi, biws0, 256, flags);
                const ushort_t* Ain = (l == 0) ? feat : h1a;
                ushort_t* dest = (l == 0) ? h1a : fused;
                int ldo  = (l == 0) ? 256 : 512;
                int col0 = (l == 0) ? 0 : g * 256;
                int act  = (l == 0) ? 1 : 0;
                if (nch == 1) {
                    gemm_bt<<<dim3(MT, 18), 256, 0, stream>>>(
                        Ain, 256, wcat, 256, tbuf, NC, 0, flags + 1, nullptr,
                        NN, NC, 256, 0);
                    k_agg_full<<<NN / 4, 256, 0, stream>>>(tbuf, NC, 0, rs[g],
                                                           deg[g], sorted[g],
                                                           biws0, dest, ldo, col0,
                                                           act, NN);
                } else {
                    for (int c = 0; c < nch; ++c) {
                        int b0 = c * C;
                        int b1 = (b0 + C < 9) ? b0 + C : 9;
                        int nb = b1 - b0;
                        gemm_bt<<<dim3(MT, nb * 2), 256, 0, stream>>>(
                            Ain, 256, wcat + (size_t)b0 * 256 * 256, 256,
                            tbuf, nb * 256, 0, flags + 1, nullptr, NN, nb * 256,
                            256, 0);
                        int fl = (c == 0 ? 1 : 0) | (c == nch - 1 ? 2 : 0);
                        k_agg2<<<NN / 4, 256, 0, stream>>>(tbuf, nb * 256, rs[g],
                                                           deg[g], sorted[g],
                                                           biws0, accf, dest, ldo,
                                                           col0, act, b0, b1, fl, NN);
                    }
                }
            }
        }
    }

    // --- fusion + exact GELU (output dtype follows input dtype) ---
    gemm_bt<<<dim3(MT, 2), 256, 0, stream>>>(fused, 512, wft, 512,
                                             d_out, 256, 0, flags, biascat,
                                             NN, 256, 512, 2);
}